// Round 24
// baseline (154.761 us; speedup 1.0000x reference)
//
#include <hip/hip_runtime.h>
#include <math.h>

// Problem constants
#define NB 4
#define NC 64
#define NPTS 4096
#define NROWS (NB*NPTS)      // 16384

typedef __attribute__((ext_vector_type(4))) float f32x4;
typedef __bf16 bf16x8 __attribute__((ext_vector_type(8)));

__device__ __forceinline__ ushort f2bf(float f) {
  unsigned u = __float_as_uint(f);
  u = (u + 0x7FFFu + ((u >> 16) & 1u)) >> 16;   // RNE
  return (ushort)u;
}
__device__ __forceinline__ unsigned pk2(float lo, float hi) {
  return (unsigned)f2bf(lo) | ((unsigned)f2bf(hi) << 16);
}

// ---------------- top-16 insertion (sorted ascending, dd[15]=max) -------------
__device__ __forceinline__ void insert16(double dist, int j, double (&dd)[16], int (&ii)[16]) {
  double cd = dist; int ci = j;
#pragma unroll
  for (int s = 0; s < 16; ++s) {
    double od = dd[s]; int oi = ii[s];
    bool c = cd < od;
    dd[s] = c ? cd : od;
    ii[s] = c ? ci : oi;
    cd = c ? od : cd;
    ci = c ? oi : ci;
  }
}

__device__ __forceinline__ void bub16u(unsigned key, unsigned (&t)[16]) {
#pragma unroll
  for (int q2 = 0; q2 < 16; ++q2) {
    unsigned lo = min(key, t[q2]);
    key = max(key, t[q2]);
    t[q2] = lo;
  }
}

// DPP row_ror double helper (rotates both 32-bit halves by the same lanes)
#define DPPD(RES, V, CTRL) { \
  long long bits_ = __double_as_longlong(V); \
  int lo_ = (int)bits_, hi_ = (int)(bits_ >> 32); \
  int lo2_ = __builtin_amdgcn_update_dpp(0, lo_, CTRL, 0xF, 0xF, true); \
  int hi2_ = __builtin_amdgcn_update_dpp(0, hi_, CTRL, 0xF, 0xF, true); \
  RES = __longlong_as_double(((long long)(unsigned)lo2_) | ((long long)hi2_ << 32)); }

// full-wave f64 sum: DPP rotate-reduce within 16-lane rows, then 2 cross-row shfls
__device__ __forceinline__ double wave_reduce(double v) {
  double t2;
  DPPD(t2, v, 0x121) v += t2;
  DPPD(t2, v, 0x122) v += t2;
  DPPD(t2, v, 0x124) v += t2;
  DPPD(t2, v, 0x128) v += t2;
  v += __shfl_xor(v, 16, 64);
  v += __shfl_xor(v, 32, 64);
  return v;
}

// ---------------- Kernel P: fused prep (pack pos4 | transpose inT | pack LTf) --
__global__ __launch_bounds__(256) void prep_all(const float* __restrict__ pos,
                                                float4* __restrict__ pos4,
                                                const float* __restrict__ in,
                                                ushort* __restrict__ inT,
                                                const float* __restrict__ lin_w,
                                                ushort* __restrict__ LTf) {
  __shared__ float tile[64][68];
  int t = threadIdx.x;
  int bid = blockIdx.x;
  if (bid < 64) {
    int g = bid * 256 + t;
    int b = g >> 12, n = g & (NPTS - 1);
    const float* pb = pos + b * 3 * NPTS;
    pos4[g] = make_float4(pb[n], pb[NPTS + n], pb[2 * NPTS + n], 0.f);
  } else if (bid < 320) {
    int blk = bid - 64;
    int b = blk >> 6;
    int n0 = (blk & 63) << 6;
    {
      int c = t >> 2, q = t & 3;
      const float* src = in + ((size_t)(b * 64 + c)) * NPTS + n0 + q * 16;
      float4 v0 = ((const float4*)src)[0];
      float4 v1 = ((const float4*)src)[1];
      float4 v2 = ((const float4*)src)[2];
      float4 v3 = ((const float4*)src)[3];
      *(float4*)&tile[c][q * 16 + 0] = v0;
      *(float4*)&tile[c][q * 16 + 4] = v1;
      *(float4*)&tile[c][q * 16 + 8] = v2;
      *(float4*)&tile[c][q * 16 + 12] = v3;
    }
    __syncthreads();
    {
      int nl = t >> 2, cq = t & 3;
      unsigned pk[8];
#pragma unroll
      for (int i = 0; i < 8; ++i) {
        float lo = tile[cq * 16 + 2 * i][nl];
        float hi = tile[cq * 16 + 2 * i + 1][nl];
        pk[i] = pk2(lo, hi);
      }
      uint4* dst = (uint4*)(inT + ((size_t)(b * NPTS + n0 + nl)) * 64 + cq * 16);
      dst[0] = make_uint4(pk[0], pk[1], pk[2], pk[3]);
      dst[1] = make_uint4(pk[4], pk[5], pk[6], pk[7]);
    }
  } else {
    int g = (bid - 320) * 256 + t;      // 16384
    int l = g & 63, ot = (g >> 6) & 3, s = g >> 8;
    int o = ot * 16 + (l & 15);
    const float* src = lin_w + (size_t)o * 2048 + s * 32 + (l >> 4) * 8;
    float4 u0 = ((const float4*)src)[0];
    float4 u1 = ((const float4*)src)[1];
    ((uint4*)LTf)[g] = make_uint4(pk2(u0.x, u0.y), pk2(u0.z, u0.w),
                                  pk2(u1.x, u1.y), pk2(u1.z, u1.w));
  }
}

// ---------------- Kernel S: subset partial KNN --------------------------------
__global__ __launch_bounds__(256) void knn_sub(const float4* __restrict__ pos4,
                                               uint4* __restrict__ partials) {
  __shared__ float4 cand[128];
  int t = threadIdx.x;
  int row0 = blockIdx.x * 256;
  int b = row0 >> 12;
  int y = blockIdx.y;
  int j0 = (y >> 1) * 1024 + (y & 1) * 128;
  const float4* pb = pos4 + b * NPTS;
  if (t < 128) cand[t] = pb[j0 + t];
  __syncthreads();
  float4 q = pb[(row0 + t) & (NPTS - 1)];
  unsigned dd[16];
#pragma unroll
  for (int s = 0; s < 16; ++s) dd[s] = 0xFFFFFFFFu;
#pragma unroll 4
  for (int jj = 0; jj < 128; ++jj) {
    float4 c = cand[jj];
    float dx = q.x - c.x, dy = q.y - c.y, dz = q.z - c.z;
    float d = fmaf(dx, dx, fmaf(dy, dy, dz * dz));
    unsigned key = (__float_as_uint(d) & 0xFFFFF000u) | (unsigned)(j0 + jj);
#pragma unroll
    for (int s = 0; s < 16; ++s) {
      unsigned lo = min(key, dd[s]);
      key = max(key, dd[s]);
      dd[s] = lo;
    }
  }
  uint4* po = partials + ((size_t)y * NROWS + row0 + t) * 4;
  po[0] = make_uint4(dd[0], dd[1], dd[2], dd[3]);
  po[1] = make_uint4(dd[4], dd[5], dd[6], dd[7]);
  po[2] = make_uint4(dd[8], dd[9], dd[10], dd[11]);
  po[3] = make_uint4(dd[12], dd[13], dd[14], dd[15]);
}

// ---------------- Kernel T: per-row filter threshold (batched LDS staging) ----
__global__ __launch_bounds__(64) void knn_thresh(const uint4* __restrict__ partials,
                                                 unsigned* __restrict__ T0g) {
  __shared__ unsigned sl[64 * 132];      // 33792 B
  int tid = threadIdx.x;
  int row0 = blockIdx.x * 64;
  uint4* sl4 = (uint4*)sl;
  size_t base = (size_t)row0 * 4 + tid;
#define TW(IT, V) { int g2 = ((IT) & 3) * 64 + tid; \
                    sl4[(g2 >> 2) * 33 + ((IT) >> 2) * 4 + (g2 & 3)] = (V); }
#define TB(B) { int IT0 = (B) * 8; \
  uint4 w0 = partials[(size_t)((IT0+0)>>2)*(NROWS*4) + ((IT0+0)&3)*64 + base]; \
  uint4 w1 = partials[(size_t)((IT0+1)>>2)*(NROWS*4) + ((IT0+1)&3)*64 + base]; \
  uint4 w2 = partials[(size_t)((IT0+2)>>2)*(NROWS*4) + ((IT0+2)&3)*64 + base]; \
  uint4 w3 = partials[(size_t)((IT0+3)>>2)*(NROWS*4) + ((IT0+3)&3)*64 + base]; \
  uint4 w4 = partials[(size_t)((IT0+4)>>2)*(NROWS*4) + ((IT0+4)&3)*64 + base]; \
  uint4 w5 = partials[(size_t)((IT0+5)>>2)*(NROWS*4) + ((IT0+5)&3)*64 + base]; \
  uint4 w6 = partials[(size_t)((IT0+6)>>2)*(NROWS*4) + ((IT0+6)&3)*64 + base]; \
  uint4 w7 = partials[(size_t)((IT0+7)>>2)*(NROWS*4) + ((IT0+7)&3)*64 + base]; \
  TW(IT0+0,w0) TW(IT0+1,w1) TW(IT0+2,w2) TW(IT0+3,w3) \
  TW(IT0+4,w4) TW(IT0+5,w5) TW(IT0+6,w6) TW(IT0+7,w7) }
  TB(0) TB(1) TB(2) TB(3)
#undef TB
#undef TW
  __syncthreads();
  unsigned top[16];
#pragma unroll
  for (int s = 0; s < 16; ++s) top[s] = 0xFFFFFFFFu;
  const unsigned* my = sl + tid * 132;
  for (int y = 0; y < 8; ++y) {
#pragma unroll 4
    for (int s = 0; s < 16; ++s) {
      unsigned key = my[y * 16 + s];
      if (key >= top[15]) break;         // chunk list sorted ascending
#pragma unroll
      for (int q2 = 0; q2 < 16; ++q2) {
        unsigned lo = min(key, top[q2]);
        key = max(key, top[q2]);
        top[q2] = lo;
      }
    }
  }
  T0g[row0 + tid] = top[15] & 0xFFFFF000u;
}

// ---------------- Kernel FF: fused scan + sort + tournament + stats -----------
// Block = 16 rows x 16 chunks (lane group g holds row g's 16 chunks). All 4096
// candidates staged once in SoA LDS (stride 258 -> conflict-free reads). Scan
// appends to LDS queue (2-op body), exec-gated sorted top-16 in regs, then the
// DPP tournament + tie-gated exact re-rank + BN stats (r23 tail, register-fed).
__global__ __launch_bounds__(256, 2) void knn_ff(const float4* __restrict__ pos4,
                                                 const float* __restrict__ invd,
                                                 const unsigned* __restrict__ T0g,
                                                 int* __restrict__ nn_idx,
                                                 float* __restrict__ dsbuf,
                                                 double* __restrict__ stp) {
  __shared__ float cx[16 * 258], cy[16 * 258], cz[16 * 258];  // 49536 B
  __shared__ unsigned lq[256 * 28];                           // 28672 B
  int t = threadIdx.x;
  int blk = blockIdx.x;
  int r = blk * 16 + (t >> 4);
  int b = r >> 12, n = r & (NPTS - 1);
  int ln = t & 15;                       // chunk id / neighbor lane
  const float4* pb = pos4 + b * NPTS;
  // ---- stage all 4096 candidates (coalesced, L2-resident) ----
#pragma unroll
  for (int i = 0; i < 16; ++i) {
    int g = i * 256 + t;
    float4 c = pb[g];
    int off = (g >> 8) * 258 + (g & 255);
    cx[off] = c.x; cy[off] = c.y; cz[off] = c.z;
  }
  __syncthreads();
  float4 q = pb[n];
  unsigned T = T0g[r];
  unsigned cnt = 0;
  unsigned* myq = lq + t * 28;
  int j0 = ln * 256;
  const float* cxp = cx + ln * 258;
  const float* cyp = cy + ln * 258;
  const float* czp = cz + ln * 258;
#pragma unroll 4
  for (int jj = 0; jj < 256; ++jj) {
    float dx = q.x - cxp[jj], dy = q.y - cyp[jj], dz = q.z - czp[jj];
    float d = fmaf(dx, dx, fmaf(dy, dy, dz * dz));
    unsigned m = __float_as_uint(d) & 0xFFFFF000u;
    if (m <= T) {
      if (cnt < 28u) myq[cnt] = m | (unsigned)(j0 + jj);
      ++cnt;
    }
  }
  cnt = cnt < 28u ? cnt : 28u;
  // ---- sorted top-16 in regs (exec-gated) ----
  unsigned t16a[16];
#pragma unroll
  for (int s = 0; s < 16; ++s) t16a[s] = 0xFFFFFFFFu;
  const uint4* qsrc = (const uint4*)myq;
  uint4 q0 = qsrc[0], q1 = qsrc[1], q2 = qsrc[2], q3 = qsrc[3],
        q4 = qsrc[4], q5 = qsrc[5], q6 = qsrc[6];
#define SIN(K, I) { if ((I) < cnt) bub16u((K), t16a); }
  SIN(q0.x,0u) SIN(q0.y,1u) SIN(q0.z,2u) SIN(q0.w,3u)
  SIN(q1.x,4u) SIN(q1.y,5u) SIN(q1.z,6u) SIN(q1.w,7u)
  SIN(q2.x,8u) SIN(q2.y,9u) SIN(q2.z,10u) SIN(q2.w,11u)
  SIN(q3.x,12u) SIN(q3.y,13u) SIN(q3.z,14u) SIN(q3.w,15u)
  SIN(q4.x,16u) SIN(q4.y,17u) SIN(q4.z,18u) SIN(q4.w,19u)
  SIN(q5.x,20u) SIN(q5.y,21u) SIN(q5.z,22u) SIN(q5.w,23u)
  SIN(q6.x,24u) SIN(q6.y,25u) SIN(q6.z,26u) SIN(q6.w,27u)
#undef SIN
  // ---- DPP tournament over the 16-lane group ----
  unsigned h0=t16a[0],h1=t16a[1],h2=t16a[2],h3=t16a[3],h4=t16a[4],h5=t16a[5],
           h6=t16a[6],h7=t16a[7],h8=t16a[8],h9=t16a[9],h10=t16a[10],h11=t16a[11],
           h12=t16a[12],h13=t16a[13],h14=t16a[14],h15=t16a[15];
  unsigned t0,t1,t2,t3,t4,t5,t6,t7,t8,t9,t10,t11,t12,t13,t14,t15,t16;
#define UMIN_DPP(M, CTRL) \
  M = min(M, (unsigned)__builtin_amdgcn_update_dpp(0, (int)(M), CTRL, 0xF, 0xF, true));
#define RND(TT) { unsigned m = h0; \
  UMIN_DPP(m, 0x121) UMIN_DPP(m, 0x122) UMIN_DPP(m, 0x124) UMIN_DPP(m, 0x128) \
  TT = m; bool pop = (h0 == m); \
  h0 = pop ? h1 : h0;  h1 = pop ? h2 : h1;  h2 = pop ? h3 : h2; \
  h3 = pop ? h4 : h3;  h4 = pop ? h5 : h4;  h5 = pop ? h6 : h5; \
  h6 = pop ? h7 : h6;  h7 = pop ? h8 : h7;  h8 = pop ? h9 : h8; \
  h9 = pop ? h10 : h9; h10 = pop ? h11 : h10; h11 = pop ? h12 : h11; \
  h12 = pop ? h13 : h12; h13 = pop ? h14 : h13; h14 = pop ? h15 : h14; \
  h15 = pop ? 0xFFFFFFFFu : h15; }
  RND(t0) RND(t1) RND(t2) RND(t3) RND(t4) RND(t5) RND(t6) RND(t7)
  RND(t8) RND(t9) RND(t10) RND(t11) RND(t12) RND(t13) RND(t14) RND(t15)
  RND(t16)

  float4 qp = q;
  double xi = qp.x, yi = qp.y, zi = qp.z;

  int jm;
  bool tie = ((t15 & 0xFFFFF000u) == (t16 & 0xFFFFF000u));
  if (!tie) {
    unsigned tm = t0;
    tm = (ln == 1) ? t1 : tm;   tm = (ln == 2) ? t2 : tm;
    tm = (ln == 3) ? t3 : tm;   tm = (ln == 4) ? t4 : tm;
    tm = (ln == 5) ? t5 : tm;   tm = (ln == 6) ? t6 : tm;
    tm = (ln == 7) ? t7 : tm;   tm = (ln == 8) ? t8 : tm;
    tm = (ln == 9) ? t9 : tm;   tm = (ln == 10) ? t10 : tm;
    tm = (ln == 11) ? t11 : tm; tm = (ln == 12) ? t12 : tm;
    tm = (ln == 13) ? t13 : tm; tm = (ln == 14) ? t14 : tm;
    tm = (ln == 15) ? t15 : tm;
    jm = (int)(tm & 0xFFFu);
  } else {
    unsigned t17, t18, t19, t20, t21, t22, t23;
    RND(t17) RND(t18) RND(t19) RND(t20) RND(t21) RND(t22) RND(t23)
    double dd[16]; int ii[16];
#pragma unroll
    for (int s = 0; s < 16; ++s) { dd[s] = 1e300; ii[s] = 0; }
#define RRK(TT) if (TT != 0xFFFFFFFFu) { int j = (int)(TT & 0xFFFu); \
  float4 cj = pb[j]; \
  double dx = xi - (double)cj.x, dy = yi - (double)cj.y, dz = zi - (double)cj.z; \
  double dist = dx * dx + dy * dy + dz * dz; \
  if (dist < dd[15]) insert16(dist, j, dd, ii); }
    RRK(t0) RRK(t1) RRK(t2) RRK(t3) RRK(t4) RRK(t5) RRK(t6) RRK(t7)
    RRK(t8) RRK(t9) RRK(t10) RRK(t11) RRK(t12) RRK(t13) RRK(t14) RRK(t15)
    RRK(t16) RRK(t17) RRK(t18) RRK(t19) RRK(t20) RRK(t21) RRK(t22) RRK(t23)
#undef RRK
    int jj2 = ii[0];
#pragma unroll
    for (int s = 1; s < 16; ++s) jj2 = (ln == s) ? ii[s] : jj2;
    jm = jj2;
  }
#undef RND
#undef UMIN_DPP

  nn_idx[(size_t)r * 16 + ln] = jm;
  const float* ivb = invd + b * NPTS;
  float v = ivb[jm];
  float vmax = v;
#define FMAX_DPP(X, CTRL) { \
    float y_ = __int_as_float(__builtin_amdgcn_update_dpp(0, __float_as_int(X), CTRL, 0xF, 0xF, true)); \
    X = fmaxf(X, y_); }
  FMAX_DPP(vmax, 0x121) FMAX_DPP(vmax, 0x122)
  FMAX_DPP(vmax, 0x124) FMAX_DPP(vmax, 0x128)
#undef FMAX_DPP
  float x = v / vmax;
  dsbuf[(size_t)r * 16 + ln] = x;

  double sx = x, sxx = (double)x * (double)x;
  float4 pj = pb[jm];
  double lx = (double)pj.x - xi, lyv = (double)pj.y - yi, lzv = (double)pj.z - zi;
  double l1x = lx, l1y = lyv, l1z = lzv;
  double lxx = lx * lx, lyy = lyv * lyv, lzz = lzv * lzv;
  double lxy = lx * lyv, lxz = lx * lzv, lyz = lyv * lzv;
  sx  = wave_reduce(sx);  sxx = wave_reduce(sxx);
  l1x = wave_reduce(l1x); l1y = wave_reduce(l1y); l1z = wave_reduce(l1z);
  lxx = wave_reduce(lxx); lyy = wave_reduce(lyy); lzz = wave_reduce(lzz);
  lxy = wave_reduce(lxy); lxz = wave_reduce(lxz); lyz = wave_reduce(lyz);
  if ((t & 63) == 0) {
    double* o = stp + ((size_t)blk * 4 + (t >> 6)) * 16;
    o[0] = sx;  o[1] = sxx;
    o[2] = l1x; o[3] = l1y; o[4] = l1z;
    o[5] = lxx; o[6] = lyy; o[7] = lzz;
    o[8] = lxy; o[9] = lxz; o[10] = lyz;
  }
}

// ---------------- Kernel 3: reduce 4096 partials + fold BN --------------------
__global__ __launch_bounds__(256) void finalize_params(const double* __restrict__ stp,
                                const float* __restrict__ wn_w,
                                const float* __restrict__ wn_g,
                                const float* __restrict__ wn_be,
                                const float* __restrict__ dn_w1,
                                const float* __restrict__ dn_g1,
                                const float* __restrict__ dn_be1,
                                float* __restrict__ prm) {
  __shared__ double part[16][16];
  __shared__ double red[11];
  const double M = (double)NROWS * 16.0;  // 262144
  int t = threadIdx.x;
  {
    int c = t & 15, ch = t >> 4;         // 16 chunks of 256 wave-partials
    double s = 0.0;
#pragma unroll 8
    for (int w = 0; w < 256; ++w) s += stp[(size_t)(ch * 256 + w) * 16 + c];
    part[ch][c] = s;
  }
  __syncthreads();
  if (t < 11) {
    double s = 0.0;
#pragma unroll
    for (int ch = 0; ch < 16; ++ch) s += part[ch][t];
    red[t] = s;
  }
  __syncthreads();
  if (t < 32) {
    double m0 = red[2] / M, m1 = red[3] / M, m2 = red[4] / M;
    double cxx = red[5] / M - m0 * m0, cyy = red[6] / M - m1 * m1, czz = red[7] / M - m2 * m2;
    double cxy = red[8] / M - m0 * m1, cxz = red[9] / M - m0 * m2, cyz = red[10] / M - m1 * m2;
    double w0 = wn_w[t * 3], w1 = wn_w[t * 3 + 1], w2 = wn_w[t * 3 + 2];
    double var = w0 * w0 * cxx + w1 * w1 * cyy + w2 * w2 * czz
               + 2.0 * (w0 * w1 * cxy + w0 * w2 * cxz + w1 * w2 * cyz);
    double alpha = (double)wn_g[t] / sqrt(var + 1e-5);
    double a0 = alpha * w0, a1 = alpha * w1, a2 = alpha * w2;
    prm[t * 3] = (float)a0; prm[t * 3 + 1] = (float)a1; prm[t * 3 + 2] = (float)a2;
    prm[96 + t] = (float)((double)wn_be[t] - (a0 * m0 + a1 * m1 + a2 * m2));
  } else if (t < 48) {
    int ch = t - 32;
    double mx = red[0] / M;
    double vx = red[1] / M - mx * mx;
    double w = dn_w1[ch];
    double alpha = (double)dn_g1[ch] * w / sqrt(w * w * vx + 1e-5);
    prm[128 + ch] = (float)alpha;
    prm[144 + ch] = (float)((double)dn_be1[ch] - alpha * mx);
  }
}

// ------- Fused kernel: gather + DensityNet + WeightNet + MFMA matmul + GEMM ---
#define XSTR 2320   // bytes per point: 16 k-rows * 144 B + 16 pad
#define WTOFF 37120 // = 16*XSTR
#define WTSTR 1040  // bytes per point: 32 w-rows * 32 B + 16 pad

__global__ __launch_bounds__(256, 3) void fused(const ushort* __restrict__ inT,
                                                const float4* __restrict__ pos4,
                                                const int* __restrict__ nn_idx,
                                                const float* __restrict__ dsbuf,
                                                const float* __restrict__ prm_g,
                                                const float* __restrict__ dn_w2,
                                                const float* __restrict__ dn_b2,
                                                const ushort* __restrict__ LTf,
                                                const float* __restrict__ lin_b,
                                                float* __restrict__ out) {
  __shared__ __align__(16) char smem[53760];
  char* xraw = smem;
  char* wT = smem + WTOFF;
  int t = threadIdx.x;
  int blk = blockIdx.x;          // 1024 tiles of 16 points
  int b = blk >> 8;
  int n0 = (blk & 255) << 4;
  // ---- phase 1: stage. thread (k = t>>4, p = t&15) ----
  {
    int k = t >> 4, p = t & 15;
    int r = blk * 16 + p;
    int n = n0 + p;
    int j = nn_idx[(size_t)r * 16 + k];
    float4 pj = pos4[b * NPTS + j];
    float4 pn = pos4[b * NPTS + n];
    float lx = pj.x - pn.x, ly = pj.y - pn.y, lz = pj.z - pn.z;
    float xr = dsbuf[(size_t)r * 16 + k];
    float sacc = dn_b2[0];
#pragma unroll
    for (int ch = 0; ch < 16; ++ch)
      sacc = fmaf(dn_w2[ch], fmaxf(fmaf(prm_g[128 + ch], xr, prm_g[144 + ch]), 0.f), sacc);
    float ds = 1.f / (1.f + expf(-sacc));
    const uint4* srcx = (const uint4*)(inT + ((size_t)(b * NPTS + j)) * 64);
    uint4* dstx = (uint4*)(xraw + p * XSTR + k * 144);
#pragma unroll
    for (int i = 0; i < 8; ++i) dstx[i] = srcx[i];
    char* wr = wT + p * WTSTR + k * 2;
#pragma unroll
    for (int w = 0; w < 32; ++w) {
      float v = fmaf(prm_g[w * 3], lx,
                fmaf(prm_g[w * 3 + 1], ly,
                fmaf(prm_g[w * 3 + 2], lz, prm_g[96 + w])));
      *(ushort*)(wr + w * 32) = f2bf(fmaxf(v, 0.f) * ds);
    }
  }
  __syncthreads();
  // ---- phase 2: MFMA per-point matmul. wave wv -> points wv*4..wv*4+3 ----
  int wv = t >> 6;
  int l = t & 63;
  int lr = l & 15;
  int q = l >> 4;
  int kq8 = (q & 1) * 1152;      // (q&1)*8 rows * 144 B
  int swz = (lr & 7) << 4;
  const f32x4 zf = (f32x4)0.f;
  uint4 zu = make_uint4(0u, 0u, 0u, 0u);

#define DECLD(IT) unsigned d##IT##_0,d##IT##_1,d##IT##_2,d##IT##_3,d##IT##_4, \
  d##IT##_5,d##IT##_6,d##IT##_7,d##IT##_8,d##IT##_9,d##IT##_10,d##IT##_11, \
  d##IT##_12,d##IT##_13,d##IT##_14,d##IT##_15;
  DECLD(0) DECLD(1) DECLD(2) DECLD(3)
#undef DECLD

#define LOADB(BU, NI, XP) { \
    const char* xb = (XP) + ((NI) * 16 + lr) * 2; \
    unsigned e0 = *(const ushort*)(xb); \
    unsigned e1 = *(const ushort*)(xb + 144); \
    unsigned e2 = *(const ushort*)(xb + 288); \
    unsigned e3 = *(const ushort*)(xb + 432); \
    unsigned e4 = *(const ushort*)(xb + 576); \
    unsigned e5 = *(const ushort*)(xb + 720); \
    unsigned e6 = *(const ushort*)(xb + 864); \
    unsigned e7 = *(const ushort*)(xb + 1008); \
    BU = make_uint4(e0 | (e1 << 16), e2 | (e3 << 16), \
                    e4 | (e5 << 16), e6 | (e7 << 16)); }

#define MM(AF, BF, RA, RB) { \
    f32x4 D = __builtin_amdgcn_mfma_f32_16x16x32_bf16(AF, BF, zf, 0, 0, 0); \
    RA = pk2(D.x, D.y); RB = pk2(D.z, D.w); }

#define DO_POINT(IT) { \
    int p = wv * 4 + (IT); \
    const char* wtp = wT + p * WTSTR; \
    const char* xp = xraw + p * XSTR + kq8; \
    uint4 a0u = zu, a1u = zu; \
    if (q < 2) { \
      a0u = *(const uint4*)(wtp + lr * 32 + q * 16); \
      a1u = *(const uint4*)(wtp + (16 + lr) * 32 + q * 16); \
    } \
    bf16x8 A0 = *reinterpret_cast<bf16x8*>(&a0u); \
    bf16x8 A1 = *reinterpret_cast<bf16x8*>(&a1u); \
    uint4 b0u, b1u, b2u, b3u; \
    LOADB(b0u, 0, xp) LOADB(b1u, 1, xp) LOADB(b2u, 2, xp) LOADB(b3u, 3, xp) \
    bf16x8 B0 = *reinterpret_cast<bf16x8*>(&b0u); \
    bf16x8 B1 = *reinterpret_cast<bf16x8*>(&b1u); \
    bf16x8 B2 = *reinterpret_cast<bf16x8*>(&b2u); \
    bf16x8 B3 = *reinterpret_cast<bf16x8*>(&b3u); \
    MM(A0, B0, d##IT##_0, d##IT##_1)   MM(A0, B1, d##IT##_2, d##IT##_3) \
    MM(A0, B2, d##IT##_4, d##IT##_5)   MM(A0, B3, d##IT##_6, d##IT##_7) \
    MM(A1, B0, d##IT##_8, d##IT##_9)   MM(A1, B1, d##IT##_10, d##IT##_11) \
    MM(A1, B2, d##IT##_12, d##IT##_13) MM(A1, B3, d##IT##_14, d##IT##_15) }

  DO_POINT(0) DO_POINT(1) DO_POINT(2) DO_POINT(3)
#undef DO_POINT
#undef MM
#undef LOADB
  __syncthreads();   // all MFMA reads of xraw/wT complete
  // ---- phases 3/4 in two K-halves over 32 KB aq aliased on xraw ----
  int hq = q >> 1;
  int m0 = (q & 1) * 2;
  const uint4* Lq = (const uint4*)LTf;
  f32x4 cacc = (f32x4)0.f;
#define STT(IT, MI, NIL, RA, RB) { \
    int p = wv * 4 + (IT); \
    int h = (MI) * 2 + hq; \
    int base = (((NIL) * 16 + lr)) * 1024 + (p + 16 * h) * 16 + m0 * 4; \
    *(unsigned*)(smem + (base ^ swz)) = RA; \
    *(unsigned*)(smem + ((base + 4) ^ swz)) = RB; }
  // half A: NI 0,1  -> local rows 0..31
#define STPA(IT) \
    STT(IT,0,0,d##IT##_0,d##IT##_1)   STT(IT,0,1,d##IT##_2,d##IT##_3) \
    STT(IT,1,0,d##IT##_8,d##IT##_9)   STT(IT,1,1,d##IT##_10,d##IT##_11)
  STPA(0) STPA(1) STPA(2) STPA(3)
#undef STPA
  __syncthreads();
#pragma unroll 4
  for (int s = 0; s < 32; ++s) {
    uint4 ua = *(const uint4*)(smem + (((s * 64 + l) * 16) ^ ((s & 7) << 4)));
    uint4 ub = Lq[(s * 4 + wv) * 64 + l];
    bf16x8 A = *reinterpret_cast<bf16x8*>(&ua);
    bf16x8 B = *reinterpret_cast<bf16x8*>(&ub);
    cacc = __builtin_amdgcn_mfma_f32_16x16x32_bf16(A, B, cacc, 0, 0, 0);
  }
  __syncthreads();   // phase-4a reads done before overwrite
  // half B: NI 2,3 -> local rows 0..31
#define STPB(IT) \
    STT(IT,0,0,d##IT##_4,d##IT##_5)   STT(IT,0,1,d##IT##_6,d##IT##_7) \
    STT(IT,1,0,d##IT##_12,d##IT##_13) STT(IT,1,1,d##IT##_14,d##IT##_15)
  STPB(0) STPB(1) STPB(2) STPB(3)
#undef STPB
#undef STT
  __syncthreads();
#pragma unroll 4
  for (int sl2 = 0; sl2 < 32; ++sl2) {
    int s = sl2 + 32;
    uint4 ua = *(const uint4*)(smem + (((sl2 * 64 + l) * 16) ^ ((sl2 & 7) << 4)));
    uint4 ub = Lq[(s * 4 + wv) * 64 + l];
    bf16x8 A = *reinterpret_cast<bf16x8*>(&ua);
    bf16x8 B = *reinterpret_cast<bf16x8*>(&ub);
    cacc = __builtin_amdgcn_mfma_f32_16x16x32_bf16(A, B, cacc, 0, 0, 0);
  }
  // ---- epilogue ----
  {
    int o = wv * 16 + lr;
    float bias = lin_b[o];
    cacc.x += bias; cacc.y += bias; cacc.z += bias; cacc.w += bias;
    *(f32x4*)(out + ((size_t)(b * 64 + o)) * NPTS + n0 + q * 4) = cacc;
  }
}

// ------------------------------- launch ---------------------------------------
extern "C" void kernel_launch(void* const* d_in, const int* in_sizes, int n_in,
                              void* d_out, int out_size, void* d_ws, size_t ws_size,
                              hipStream_t stream) {
  (void)in_sizes; (void)n_in; (void)out_size; (void)ws_size;
  const float* inputs = (const float*)d_in[0];
  const float* pos    = (const float*)d_in[1];
  const float* invd   = (const float*)d_in[2];
  const float* wn_w   = (const float*)d_in[3];
  const float* wn_g   = (const float*)d_in[5];
  const float* wn_be  = (const float*)d_in[6];
  const float* dn_w1  = (const float*)d_in[7];
  const float* dn_g1  = (const float*)d_in[9];
  const float* dn_be1 = (const float*)d_in[10];
  const float* dn_w2  = (const float*)d_in[11];
  const float* dn_b2  = (const float*)d_in[12];
  const float* lin_w  = (const float*)d_in[13];
  const float* lin_b  = (const float*)d_in[14];
  float* outp = (float*)d_out;

  char* ws = (char*)d_ws;
  float*    prm      = (float*)(ws + 1024);                   // 640 B
  float4*   pos4     = (float4*)(ws + 4096);                  // 256 KB
  int*      nnidx    = (int*)(ws + (size_t)(1u << 19));       // 1 MB   [0.5, 1.5)
  float*    dsbuf    = (float*)(ws + (size_t)(3u << 19));     // 1 MB   [1.5, 2.5)
  ushort*   inT      = (ushort*)(ws + (size_t)(5u << 19));    // 2 MB   [2.5, 4.5)
  ushort*   LTf      = (ushort*)(ws + (size_t)(9u << 19));    // 256 KB [4.5, 4.75)
  unsigned* T0g      = (unsigned*)(ws + (size_t)(19u << 18)); // 64 KB  [4.75, 4.8125)
  double*   stp      = (double*)(ws + (size_t)(5u << 20));    // 512 KB [5, 5.5)
  uint4*    partials = (uint4*)(ws + (size_t)(11u << 19));    // 8 MB   [5.5, 13.5)

  prep_all<<<384, 256, 0, stream>>>(pos, pos4, inputs, inT, lin_w, LTf);
  knn_sub<<<dim3(64, 8), 256, 0, stream>>>(pos4, partials);
  knn_thresh<<<256, 64, 0, stream>>>(partials, T0g);
  knn_ff<<<1024, 256, 0, stream>>>(pos4, invd, T0g, nnidx, dsbuf, stp);
  finalize_params<<<1, 256, 0, stream>>>(stp, wn_w, wn_g, wn_be, dn_w1, dn_g1, dn_be1, prm);
  fused<<<1024, 256, 0, stream>>>(inT, pos4, nnidx, dsbuf, prm, dn_w2, dn_b2, LTf, lin_b, outp);
}

// Round 25
// 136.409 us; speedup vs baseline: 1.1345x; 1.1345x over previous
//
#include <hip/hip_runtime.h>
#include <math.h>

// Problem constants
#define NB 4
#define NC 64
#define NPTS 4096
#define NROWS (NB*NPTS)      // 16384

typedef __attribute__((ext_vector_type(4))) float f32x4;
typedef __bf16 bf16x8 __attribute__((ext_vector_type(8)));

__device__ __forceinline__ ushort f2bf(float f) {
  unsigned u = __float_as_uint(f);
  u = (u + 0x7FFFu + ((u >> 16) & 1u)) >> 16;   // RNE
  return (ushort)u;
}
__device__ __forceinline__ unsigned pk2(float lo, float hi) {
  return (unsigned)f2bf(lo) | ((unsigned)f2bf(hi) << 16);
}

// ---------------- top-16 insertion (sorted ascending, dd[15]=max) -------------
__device__ __forceinline__ void insert16(double dist, int j, double (&dd)[16], int (&ii)[16]) {
  double cd = dist; int ci = j;
#pragma unroll
  for (int s = 0; s < 16; ++s) {
    double od = dd[s]; int oi = ii[s];
    bool c = cd < od;
    dd[s] = c ? cd : od;
    ii[s] = c ? ci : oi;
    cd = c ? od : cd;
    ci = c ? oi : ci;
  }
}

__device__ __forceinline__ void bub16u(unsigned key, unsigned (&t)[16]) {
#pragma unroll
  for (int q2 = 0; q2 < 16; ++q2) {
    unsigned lo = min(key, t[q2]);
    key = max(key, t[q2]);
    t[q2] = lo;
  }
}

// DPP row_ror double helper (rotates both 32-bit halves by the same lanes)
#define DPPD(RES, V, CTRL) { \
  long long bits_ = __double_as_longlong(V); \
  int lo_ = (int)bits_, hi_ = (int)(bits_ >> 32); \
  int lo2_ = __builtin_amdgcn_update_dpp(0, lo_, CTRL, 0xF, 0xF, true); \
  int hi2_ = __builtin_amdgcn_update_dpp(0, hi_, CTRL, 0xF, 0xF, true); \
  RES = __longlong_as_double(((long long)(unsigned)lo2_) | ((long long)hi2_ << 32)); }

// full-wave f64 sum: DPP rotate-reduce within 16-lane rows, then 2 cross-row shfls
__device__ __forceinline__ double wave_reduce(double v) {
  double t2;
  DPPD(t2, v, 0x121) v += t2;
  DPPD(t2, v, 0x122) v += t2;
  DPPD(t2, v, 0x124) v += t2;
  DPPD(t2, v, 0x128) v += t2;
  v += __shfl_xor(v, 16, 64);
  v += __shfl_xor(v, 32, 64);
  return v;
}

// ---------------- Kernel P: fused prep (pack pos4 | transpose inT | pack LTf) --
__global__ __launch_bounds__(256) void prep_all(const float* __restrict__ pos,
                                                float4* __restrict__ pos4,
                                                const float* __restrict__ in,
                                                ushort* __restrict__ inT,
                                                const float* __restrict__ lin_w,
                                                ushort* __restrict__ LTf) {
  __shared__ float tile[64][68];
  int t = threadIdx.x;
  int bid = blockIdx.x;
  if (bid < 64) {
    int g = bid * 256 + t;
    int b = g >> 12, n = g & (NPTS - 1);
    const float* pb = pos + b * 3 * NPTS;
    pos4[g] = make_float4(pb[n], pb[NPTS + n], pb[2 * NPTS + n], 0.f);
  } else if (bid < 320) {
    int blk = bid - 64;
    int b = blk >> 6;
    int n0 = (blk & 63) << 6;
    {
      int c = t >> 2, q = t & 3;
      const float* src = in + ((size_t)(b * 64 + c)) * NPTS + n0 + q * 16;
      float4 v0 = ((const float4*)src)[0];
      float4 v1 = ((const float4*)src)[1];
      float4 v2 = ((const float4*)src)[2];
      float4 v3 = ((const float4*)src)[3];
      *(float4*)&tile[c][q * 16 + 0] = v0;
      *(float4*)&tile[c][q * 16 + 4] = v1;
      *(float4*)&tile[c][q * 16 + 8] = v2;
      *(float4*)&tile[c][q * 16 + 12] = v3;
    }
    __syncthreads();
    {
      int nl = t >> 2, cq = t & 3;
      unsigned pk[8];
#pragma unroll
      for (int i = 0; i < 8; ++i) {
        float lo = tile[cq * 16 + 2 * i][nl];
        float hi = tile[cq * 16 + 2 * i + 1][nl];
        pk[i] = pk2(lo, hi);
      }
      uint4* dst = (uint4*)(inT + ((size_t)(b * NPTS + n0 + nl)) * 64 + cq * 16);
      dst[0] = make_uint4(pk[0], pk[1], pk[2], pk[3]);
      dst[1] = make_uint4(pk[4], pk[5], pk[6], pk[7]);
    }
  } else {
    int g = (bid - 320) * 256 + t;      // 16384
    int l = g & 63, ot = (g >> 6) & 3, s = g >> 8;
    int o = ot * 16 + (l & 15);
    const float* src = lin_w + (size_t)o * 2048 + s * 32 + (l >> 4) * 8;
    float4 u0 = ((const float4*)src)[0];
    float4 u1 = ((const float4*)src)[1];
    ((uint4*)LTf)[g] = make_uint4(pk2(u0.x, u0.y), pk2(u0.z, u0.w),
                                  pk2(u1.x, u1.y), pk2(u1.z, u1.w));
  }
}

// ---------------- Kernel S: subset partial KNN --------------------------------
__global__ __launch_bounds__(256) void knn_sub(const float4* __restrict__ pos4,
                                               uint4* __restrict__ partials) {
  __shared__ float4 cand[128];
  int t = threadIdx.x;
  int row0 = blockIdx.x * 256;
  int b = row0 >> 12;
  int y = blockIdx.y;
  int j0 = (y >> 1) * 1024 + (y & 1) * 128;
  const float4* pb = pos4 + b * NPTS;
  if (t < 128) cand[t] = pb[j0 + t];
  __syncthreads();
  float4 q = pb[(row0 + t) & (NPTS - 1)];
  unsigned dd[16];
#pragma unroll
  for (int s = 0; s < 16; ++s) dd[s] = 0xFFFFFFFFu;
#pragma unroll 4
  for (int jj = 0; jj < 128; ++jj) {
    float4 c = cand[jj];
    float dx = q.x - c.x, dy = q.y - c.y, dz = q.z - c.z;
    float d = fmaf(dx, dx, fmaf(dy, dy, dz * dz));
    unsigned key = (__float_as_uint(d) & 0xFFFFF000u) | (unsigned)(j0 + jj);
#pragma unroll
    for (int s = 0; s < 16; ++s) {
      unsigned lo = min(key, dd[s]);
      key = max(key, dd[s]);
      dd[s] = lo;
    }
  }
  uint4* po = partials + ((size_t)y * NROWS + row0 + t) * 4;
  po[0] = make_uint4(dd[0], dd[1], dd[2], dd[3]);
  po[1] = make_uint4(dd[4], dd[5], dd[6], dd[7]);
  po[2] = make_uint4(dd[8], dd[9], dd[10], dd[11]);
  po[3] = make_uint4(dd[12], dd[13], dd[14], dd[15]);
}

// ---------------- Kernel T: per-row filter threshold (batched LDS staging) ----
__global__ __launch_bounds__(64) void knn_thresh(const uint4* __restrict__ partials,
                                                 unsigned* __restrict__ T0g) {
  __shared__ unsigned sl[64 * 132];      // 33792 B
  int tid = threadIdx.x;
  int row0 = blockIdx.x * 64;
  uint4* sl4 = (uint4*)sl;
  size_t base = (size_t)row0 * 4 + tid;
#define TW(IT, V) { int g2 = ((IT) & 3) * 64 + tid; \
                    sl4[(g2 >> 2) * 33 + ((IT) >> 2) * 4 + (g2 & 3)] = (V); }
#define TB(B) { int IT0 = (B) * 8; \
  uint4 w0 = partials[(size_t)((IT0+0)>>2)*(NROWS*4) + ((IT0+0)&3)*64 + base]; \
  uint4 w1 = partials[(size_t)((IT0+1)>>2)*(NROWS*4) + ((IT0+1)&3)*64 + base]; \
  uint4 w2 = partials[(size_t)((IT0+2)>>2)*(NROWS*4) + ((IT0+2)&3)*64 + base]; \
  uint4 w3 = partials[(size_t)((IT0+3)>>2)*(NROWS*4) + ((IT0+3)&3)*64 + base]; \
  uint4 w4 = partials[(size_t)((IT0+4)>>2)*(NROWS*4) + ((IT0+4)&3)*64 + base]; \
  uint4 w5 = partials[(size_t)((IT0+5)>>2)*(NROWS*4) + ((IT0+5)&3)*64 + base]; \
  uint4 w6 = partials[(size_t)((IT0+6)>>2)*(NROWS*4) + ((IT0+6)&3)*64 + base]; \
  uint4 w7 = partials[(size_t)((IT0+7)>>2)*(NROWS*4) + ((IT0+7)&3)*64 + base]; \
  TW(IT0+0,w0) TW(IT0+1,w1) TW(IT0+2,w2) TW(IT0+3,w3) \
  TW(IT0+4,w4) TW(IT0+5,w5) TW(IT0+6,w6) TW(IT0+7,w7) }
  TB(0) TB(1) TB(2) TB(3)
#undef TB
#undef TW
  __syncthreads();
  unsigned top[16];
#pragma unroll
  for (int s = 0; s < 16; ++s) top[s] = 0xFFFFFFFFu;
  const unsigned* my = sl + tid * 132;
  for (int y = 0; y < 8; ++y) {
#pragma unroll 4
    for (int s = 0; s < 16; ++s) {
      unsigned key = my[y * 16 + s];
      if (key >= top[15]) break;         // chunk list sorted ascending
#pragma unroll
      for (int q2 = 0; q2 < 16; ++q2) {
        unsigned lo = min(key, top[q2]);
        key = max(key, top[q2]);
        top[q2] = lo;
      }
    }
  }
  T0g[row0 + tid] = top[15] & 0xFFFFF000u;
}

// ---------------- Kernel F: scan 256-cand chunk + exec-gated sorted top-16 ----
__global__ __launch_bounds__(256) void knn_filter(const float4* __restrict__ pos4,
                                                  const unsigned* __restrict__ T0g,
                                                  uint4* __restrict__ surv) {
  __shared__ float4 cand[256];           // 4 KB
  __shared__ unsigned lq[256 * 28];      // 28 KB
  int t = threadIdx.x;
  int row0 = blockIdx.x * 256;
  int b = row0 >> 12;
  int y = blockIdx.y;
  int j0 = y * 256;
  const float4* pb = pos4 + b * NPTS;
  cand[t] = pb[j0 + t];
  __syncthreads();
  int r = row0 + t;
  float4 q = pb[r & (NPTS - 1)];
  unsigned T = T0g[r];
  unsigned cnt = 0;
  unsigned* myq = lq + t * 28;
#pragma unroll 4
  for (int jj = 0; jj < 256; ++jj) {
    float4 c = cand[jj];
    float dx = q.x - c.x, dy = q.y - c.y, dz = q.z - c.z;
    float d = fmaf(dx, dx, fmaf(dy, dy, dz * dz));
    unsigned m = __float_as_uint(d) & 0xFFFFF000u;
    if (m <= T) {
      if (cnt < 28u) myq[cnt] = m | (unsigned)(j0 + jj);
      ++cnt;
    }
  }
  cnt = cnt < 28u ? cnt : 28u;
  unsigned t16[16];
#pragma unroll
  for (int s = 0; s < 16; ++s) t16[s] = 0xFFFFFFFFu;
  const uint4* qsrc = (const uint4*)myq;
  uint4 q0 = qsrc[0], q1 = qsrc[1], q2 = qsrc[2], q3 = qsrc[3],
        q4 = qsrc[4], q5 = qsrc[5], q6 = qsrc[6];
#define SIN(K, I) { if ((I) < cnt) bub16u((K), t16); }
  SIN(q0.x,0u) SIN(q0.y,1u) SIN(q0.z,2u) SIN(q0.w,3u)
  SIN(q1.x,4u) SIN(q1.y,5u) SIN(q1.z,6u) SIN(q1.w,7u)
  SIN(q2.x,8u) SIN(q2.y,9u) SIN(q2.z,10u) SIN(q2.w,11u)
  SIN(q3.x,12u) SIN(q3.y,13u) SIN(q3.z,14u) SIN(q3.w,15u)
  SIN(q4.x,16u) SIN(q4.y,17u) SIN(q4.z,18u) SIN(q4.w,19u)
  SIN(q5.x,20u) SIN(q5.y,21u) SIN(q5.z,22u) SIN(q5.w,23u)
  SIN(q6.x,24u) SIN(q6.y,25u) SIN(q6.z,26u) SIN(q6.w,27u)
#undef SIN
  uint4* dst = surv + ((size_t)r * 16 + y) * 4;
  dst[0] = make_uint4(t16[0], t16[1], t16[2], t16[3]);
  dst[1] = make_uint4(t16[4], t16[5], t16[6], t16[7]);
  dst[2] = make_uint4(t16[8], t16[9], t16[10], t16[11]);
  dst[3] = make_uint4(t16[12], t16[13], t16[14], t16[15]);
}

// ---------------- Kernel M: DPP tournament merge + tie-gated exact re-rank ----
__global__ __launch_bounds__(256) void knn_final(const float4* __restrict__ pos4,
                                                 const float* __restrict__ invd,
                                                 const uint4* __restrict__ surv,
                                                 int* __restrict__ nn_idx,
                                                 float* __restrict__ dsbuf,
                                                 double* __restrict__ stp) {
  int t = threadIdx.x;
  int ln = t & 15;                       // lane within row-group = chunk id
  int r = blockIdx.x * 16 + (t >> 4);
  int b = r >> 12, n = r & (NPTS - 1);

  const uint4* sp = surv + ((size_t)r * 16 + ln) * 4;
  uint4 u0 = sp[0], u1 = sp[1], u2 = sp[2], u3 = sp[3];
  unsigned h0=u0.x,h1=u0.y,h2=u0.z,h3=u0.w,h4=u1.x,h5=u1.y,h6=u1.z,h7=u1.w,
           h8=u2.x,h9=u2.y,h10=u2.z,h11=u2.w,h12=u3.x,h13=u3.y,h14=u3.z,h15=u3.w;
  unsigned t0,t1,t2,t3,t4,t5,t6,t7,t8,t9,t10,t11,t12,t13,t14,t15,t16;
#define UMIN_DPP(M, CTRL) \
  M = min(M, (unsigned)__builtin_amdgcn_update_dpp(0, (int)(M), CTRL, 0xF, 0xF, true));
#define RND(TT) { unsigned m = h0; \
  UMIN_DPP(m, 0x121) UMIN_DPP(m, 0x122) UMIN_DPP(m, 0x124) UMIN_DPP(m, 0x128) \
  TT = m; bool pop = (h0 == m); \
  h0 = pop ? h1 : h0;  h1 = pop ? h2 : h1;  h2 = pop ? h3 : h2; \
  h3 = pop ? h4 : h3;  h4 = pop ? h5 : h4;  h5 = pop ? h6 : h5; \
  h6 = pop ? h7 : h6;  h7 = pop ? h8 : h7;  h8 = pop ? h9 : h8; \
  h9 = pop ? h10 : h9; h10 = pop ? h11 : h10; h11 = pop ? h12 : h11; \
  h12 = pop ? h13 : h12; h13 = pop ? h14 : h13; h14 = pop ? h15 : h14; \
  h15 = pop ? 0xFFFFFFFFu : h15; }
  RND(t0) RND(t1) RND(t2) RND(t3) RND(t4) RND(t5) RND(t6) RND(t7)
  RND(t8) RND(t9) RND(t10) RND(t11) RND(t12) RND(t13) RND(t14) RND(t15)
  RND(t16)

  const float4* pb = pos4 + b * NPTS;
  float4 qp = pb[n];
  double xi = qp.x, yi = qp.y, zi = qp.z;

  int jm;
  bool tie = ((t15 & 0xFFFFF000u) == (t16 & 0xFFFFF000u));
  if (!tie) {
    unsigned tm = t0;
    tm = (ln == 1) ? t1 : tm;   tm = (ln == 2) ? t2 : tm;
    tm = (ln == 3) ? t3 : tm;   tm = (ln == 4) ? t4 : tm;
    tm = (ln == 5) ? t5 : tm;   tm = (ln == 6) ? t6 : tm;
    tm = (ln == 7) ? t7 : tm;   tm = (ln == 8) ? t8 : tm;
    tm = (ln == 9) ? t9 : tm;   tm = (ln == 10) ? t10 : tm;
    tm = (ln == 11) ? t11 : tm; tm = (ln == 12) ? t12 : tm;
    tm = (ln == 13) ? t13 : tm; tm = (ln == 14) ? t14 : tm;
    tm = (ln == 15) ? t15 : tm;
    jm = (int)(tm & 0xFFFu);
  } else {
    unsigned t17, t18, t19, t20, t21, t22, t23;
    RND(t17) RND(t18) RND(t19) RND(t20) RND(t21) RND(t22) RND(t23)
    double dd[16]; int ii[16];
#pragma unroll
    for (int s = 0; s < 16; ++s) { dd[s] = 1e300; ii[s] = 0; }
#define RRK(TT) if (TT != 0xFFFFFFFFu) { int j = (int)(TT & 0xFFFu); \
  float4 cj = pb[j]; \
  double dx = xi - (double)cj.x, dy = yi - (double)cj.y, dz = zi - (double)cj.z; \
  double dist = dx * dx + dy * dy + dz * dz; \
  if (dist < dd[15]) insert16(dist, j, dd, ii); }
    RRK(t0) RRK(t1) RRK(t2) RRK(t3) RRK(t4) RRK(t5) RRK(t6) RRK(t7)
    RRK(t8) RRK(t9) RRK(t10) RRK(t11) RRK(t12) RRK(t13) RRK(t14) RRK(t15)
    RRK(t16) RRK(t17) RRK(t18) RRK(t19) RRK(t20) RRK(t21) RRK(t22) RRK(t23)
#undef RRK
    int jj2 = ii[0];
#pragma unroll
    for (int s = 1; s < 16; ++s) jj2 = (ln == s) ? ii[s] : jj2;
    jm = jj2;
  }
#undef RND
#undef UMIN_DPP

  nn_idx[(size_t)r * 16 + ln] = jm;
  const float* ivb = invd + b * NPTS;
  float v = ivb[jm];
  float vmax = v;
#define FMAX_DPP(X, CTRL) { \
    float y_ = __int_as_float(__builtin_amdgcn_update_dpp(0, __float_as_int(X), CTRL, 0xF, 0xF, true)); \
    X = fmaxf(X, y_); }
  FMAX_DPP(vmax, 0x121) FMAX_DPP(vmax, 0x122)
  FMAX_DPP(vmax, 0x124) FMAX_DPP(vmax, 0x128)
#undef FMAX_DPP
  float x = v / vmax;
  dsbuf[(size_t)r * 16 + ln] = x;

  double sx = x, sxx = (double)x * (double)x;
  float4 pj = pb[jm];
  double lx = (double)pj.x - xi, lyv = (double)pj.y - yi, lzv = (double)pj.z - zi;
  double l1x = lx, l1y = lyv, l1z = lzv;
  double lxx = lx * lx, lyy = lyv * lyv, lzz = lzv * lzv;
  double lxy = lx * lyv, lxz = lx * lzv, lyz = lyv * lzv;
  sx  = wave_reduce(sx);  sxx = wave_reduce(sxx);
  l1x = wave_reduce(l1x); l1y = wave_reduce(l1y); l1z = wave_reduce(l1z);
  lxx = wave_reduce(lxx); lyy = wave_reduce(lyy); lzz = wave_reduce(lzz);
  lxy = wave_reduce(lxy); lxz = wave_reduce(lxz); lyz = wave_reduce(lyz);
  if ((t & 63) == 0) {
    double* o = stp + ((size_t)blockIdx.x * 4 + (t >> 6)) * 16;
    o[0] = sx;  o[1] = sxx;
    o[2] = l1x; o[3] = l1y; o[4] = l1z;
    o[5] = lxx; o[6] = lyy; o[7] = lzz;
    o[8] = lxy; o[9] = lxz; o[10] = lyz;
  }
}

// ---------------- Kernel 3: reduce 4096 partials + fold BN --------------------
__global__ __launch_bounds__(256) void finalize_params(const double* __restrict__ stp,
                                const float* __restrict__ wn_w,
                                const float* __restrict__ wn_g,
                                const float* __restrict__ wn_be,
                                const float* __restrict__ dn_w1,
                                const float* __restrict__ dn_g1,
                                const float* __restrict__ dn_be1,
                                float* __restrict__ prm) {
  __shared__ double part[16][16];
  __shared__ double red[11];
  const double M = (double)NROWS * 16.0;  // 262144
  int t = threadIdx.x;
  {
    int c = t & 15, ch = t >> 4;         // 16 chunks of 256 wave-partials
    double s = 0.0;
#pragma unroll 8
    for (int w = 0; w < 256; ++w) s += stp[(size_t)(ch * 256 + w) * 16 + c];
    part[ch][c] = s;
  }
  __syncthreads();
  if (t < 11) {
    double s = 0.0;
#pragma unroll
    for (int ch = 0; ch < 16; ++ch) s += part[ch][t];
    red[t] = s;
  }
  __syncthreads();
  if (t < 32) {
    double m0 = red[2] / M, m1 = red[3] / M, m2 = red[4] / M;
    double cxx = red[5] / M - m0 * m0, cyy = red[6] / M - m1 * m1, czz = red[7] / M - m2 * m2;
    double cxy = red[8] / M - m0 * m1, cxz = red[9] / M - m0 * m2, cyz = red[10] / M - m1 * m2;
    double w0 = wn_w[t * 3], w1 = wn_w[t * 3 + 1], w2 = wn_w[t * 3 + 2];
    double var = w0 * w0 * cxx + w1 * w1 * cyy + w2 * w2 * czz
               + 2.0 * (w0 * w1 * cxy + w0 * w2 * cxz + w1 * w2 * cyz);
    double alpha = (double)wn_g[t] / sqrt(var + 1e-5);
    double a0 = alpha * w0, a1 = alpha * w1, a2 = alpha * w2;
    prm[t * 3] = (float)a0; prm[t * 3 + 1] = (float)a1; prm[t * 3 + 2] = (float)a2;
    prm[96 + t] = (float)((double)wn_be[t] - (a0 * m0 + a1 * m1 + a2 * m2));
  } else if (t < 48) {
    int ch = t - 32;
    double mx = red[0] / M;
    double vx = red[1] / M - mx * mx;
    double w = dn_w1[ch];
    double alpha = (double)dn_g1[ch] * w / sqrt(w * w * vx + 1e-5);
    prm[128 + ch] = (float)alpha;
    prm[144 + ch] = (float)((double)dn_be1[ch] - alpha * mx);
  }
}

// ------- Fused kernel: gather + DensityNet + WeightNet + MFMA matmul + GEMM ---
#define XSTR 2320   // bytes per point: 16 k-rows * 144 B + 16 pad
#define WTOFF 37120 // = 16*XSTR
#define WTSTR 1040  // bytes per point: 32 w-rows * 32 B + 16 pad

__global__ __launch_bounds__(256, 3) void fused(const ushort* __restrict__ inT,
                                                const float4* __restrict__ pos4,
                                                const int* __restrict__ nn_idx,
                                                const float* __restrict__ dsbuf,
                                                const float* __restrict__ prm_g,
                                                const float* __restrict__ dn_w2,
                                                const float* __restrict__ dn_b2,
                                                const ushort* __restrict__ LTf,
                                                const float* __restrict__ lin_b,
                                                float* __restrict__ out) {
  __shared__ __align__(16) char smem[53760];
  char* xraw = smem;
  char* wT = smem + WTOFF;
  int t = threadIdx.x;
  int blk = blockIdx.x;          // 1024 tiles of 16 points
  int b = blk >> 8;
  int n0 = (blk & 255) << 4;
  // ---- phase 1: stage. thread (k = t>>4, p = t&15) ----
  {
    int k = t >> 4, p = t & 15;
    int r = blk * 16 + p;
    int n = n0 + p;
    int j = nn_idx[(size_t)r * 16 + k];
    float4 pj = pos4[b * NPTS + j];
    float4 pn = pos4[b * NPTS + n];
    float lx = pj.x - pn.x, ly = pj.y - pn.y, lz = pj.z - pn.z;
    float xr = dsbuf[(size_t)r * 16 + k];
    float sacc = dn_b2[0];
#pragma unroll
    for (int ch = 0; ch < 16; ++ch)
      sacc = fmaf(dn_w2[ch], fmaxf(fmaf(prm_g[128 + ch], xr, prm_g[144 + ch]), 0.f), sacc);
    float ds = 1.f / (1.f + expf(-sacc));
    const uint4* srcx = (const uint4*)(inT + ((size_t)(b * NPTS + j)) * 64);
    uint4* dstx = (uint4*)(xraw + p * XSTR + k * 144);
#pragma unroll
    for (int i = 0; i < 8; ++i) dstx[i] = srcx[i];
    char* wr = wT + p * WTSTR + k * 2;
#pragma unroll
    for (int w = 0; w < 32; ++w) {
      float v = fmaf(prm_g[w * 3], lx,
                fmaf(prm_g[w * 3 + 1], ly,
                fmaf(prm_g[w * 3 + 2], lz, prm_g[96 + w])));
      *(ushort*)(wr + w * 32) = f2bf(fmaxf(v, 0.f) * ds);
    }
  }
  __syncthreads();
  // ---- phase 2: MFMA per-point matmul. wave wv -> points wv*4..wv*4+3 ----
  int wv = t >> 6;
  int l = t & 63;
  int lr = l & 15;
  int q = l >> 4;
  int kq8 = (q & 1) * 1152;      // (q&1)*8 rows * 144 B
  int swz = (lr & 7) << 4;
  const f32x4 zf = (f32x4)0.f;
  uint4 zu = make_uint4(0u, 0u, 0u, 0u);

#define DECLD(IT) unsigned d##IT##_0,d##IT##_1,d##IT##_2,d##IT##_3,d##IT##_4, \
  d##IT##_5,d##IT##_6,d##IT##_7,d##IT##_8,d##IT##_9,d##IT##_10,d##IT##_11, \
  d##IT##_12,d##IT##_13,d##IT##_14,d##IT##_15;
  DECLD(0) DECLD(1) DECLD(2) DECLD(3)
#undef DECLD

#define LOADB(BU, NI, XP) { \
    const char* xb = (XP) + ((NI) * 16 + lr) * 2; \
    unsigned e0 = *(const ushort*)(xb); \
    unsigned e1 = *(const ushort*)(xb + 144); \
    unsigned e2 = *(const ushort*)(xb + 288); \
    unsigned e3 = *(const ushort*)(xb + 432); \
    unsigned e4 = *(const ushort*)(xb + 576); \
    unsigned e5 = *(const ushort*)(xb + 720); \
    unsigned e6 = *(const ushort*)(xb + 864); \
    unsigned e7 = *(const ushort*)(xb + 1008); \
    BU = make_uint4(e0 | (e1 << 16), e2 | (e3 << 16), \
                    e4 | (e5 << 16), e6 | (e7 << 16)); }

#define MM(AF, BF, RA, RB) { \
    f32x4 D = __builtin_amdgcn_mfma_f32_16x16x32_bf16(AF, BF, zf, 0, 0, 0); \
    RA = pk2(D.x, D.y); RB = pk2(D.z, D.w); }

#define DO_POINT(IT) { \
    int p = wv * 4 + (IT); \
    const char* wtp = wT + p * WTSTR; \
    const char* xp = xraw + p * XSTR + kq8; \
    uint4 a0u = zu, a1u = zu; \
    if (q < 2) { \
      a0u = *(const uint4*)(wtp + lr * 32 + q * 16); \
      a1u = *(const uint4*)(wtp + (16 + lr) * 32 + q * 16); \
    } \
    bf16x8 A0 = *reinterpret_cast<bf16x8*>(&a0u); \
    bf16x8 A1 = *reinterpret_cast<bf16x8*>(&a1u); \
    uint4 b0u, b1u, b2u, b3u; \
    LOADB(b0u, 0, xp) LOADB(b1u, 1, xp) LOADB(b2u, 2, xp) LOADB(b3u, 3, xp) \
    bf16x8 B0 = *reinterpret_cast<bf16x8*>(&b0u); \
    bf16x8 B1 = *reinterpret_cast<bf16x8*>(&b1u); \
    bf16x8 B2 = *reinterpret_cast<bf16x8*>(&b2u); \
    bf16x8 B3 = *reinterpret_cast<bf16x8*>(&b3u); \
    MM(A0, B0, d##IT##_0, d##IT##_1)   MM(A0, B1, d##IT##_2, d##IT##_3) \
    MM(A0, B2, d##IT##_4, d##IT##_5)   MM(A0, B3, d##IT##_6, d##IT##_7) \
    MM(A1, B0, d##IT##_8, d##IT##_9)   MM(A1, B1, d##IT##_10, d##IT##_11) \
    MM(A1, B2, d##IT##_12, d##IT##_13) MM(A1, B3, d##IT##_14, d##IT##_15) }

  DO_POINT(0) DO_POINT(1) DO_POINT(2) DO_POINT(3)
#undef DO_POINT
#undef MM
#undef LOADB
  __syncthreads();   // all MFMA reads of xraw/wT complete
  // ---- phases 3/4 in two K-halves over 32 KB aq aliased on xraw ----
  int hq = q >> 1;
  int m0 = (q & 1) * 2;
  const uint4* Lq = (const uint4*)LTf;
  f32x4 cacc = (f32x4)0.f;
#define STT(IT, MI, NIL, RA, RB) { \
    int p = wv * 4 + (IT); \
    int h = (MI) * 2 + hq; \
    int base = (((NIL) * 16 + lr)) * 1024 + (p + 16 * h) * 16 + m0 * 4; \
    *(unsigned*)(smem + (base ^ swz)) = RA; \
    *(unsigned*)(smem + ((base + 4) ^ swz)) = RB; }
  // half A: NI 0,1  -> local rows 0..31
#define STPA(IT) \
    STT(IT,0,0,d##IT##_0,d##IT##_1)   STT(IT,0,1,d##IT##_2,d##IT##_3) \
    STT(IT,1,0,d##IT##_8,d##IT##_9)   STT(IT,1,1,d##IT##_10,d##IT##_11)
  STPA(0) STPA(1) STPA(2) STPA(3)
#undef STPA
  __syncthreads();
#pragma unroll 4
  for (int s = 0; s < 32; ++s) {
    uint4 ua = *(const uint4*)(smem + (((s * 64 + l) * 16) ^ ((s & 7) << 4)));
    uint4 ub = Lq[(s * 4 + wv) * 64 + l];
    bf16x8 A = *reinterpret_cast<bf16x8*>(&ua);
    bf16x8 B = *reinterpret_cast<bf16x8*>(&ub);
    cacc = __builtin_amdgcn_mfma_f32_16x16x32_bf16(A, B, cacc, 0, 0, 0);
  }
  __syncthreads();   // phase-4a reads done before overwrite
  // half B: NI 2,3 -> local rows 0..31
#define STPB(IT) \
    STT(IT,0,0,d##IT##_4,d##IT##_5)   STT(IT,0,1,d##IT##_6,d##IT##_7) \
    STT(IT,1,0,d##IT##_12,d##IT##_13) STT(IT,1,1,d##IT##_14,d##IT##_15)
  STPB(0) STPB(1) STPB(2) STPB(3)
#undef STPB
#undef STT
  __syncthreads();
#pragma unroll 4
  for (int sl2 = 0; sl2 < 32; ++sl2) {
    int s = sl2 + 32;
    uint4 ua = *(const uint4*)(smem + (((sl2 * 64 + l) * 16) ^ ((sl2 & 7) << 4)));
    uint4 ub = Lq[(s * 4 + wv) * 64 + l];
    bf16x8 A = *reinterpret_cast<bf16x8*>(&ua);
    bf16x8 B = *reinterpret_cast<bf16x8*>(&ub);
    cacc = __builtin_amdgcn_mfma_f32_16x16x32_bf16(A, B, cacc, 0, 0, 0);
  }
  // ---- epilogue ----
  {
    int o = wv * 16 + lr;
    float bias = lin_b[o];
    cacc.x += bias; cacc.y += bias; cacc.z += bias; cacc.w += bias;
    *(f32x4*)(out + ((size_t)(b * 64 + o)) * NPTS + n0 + q * 4) = cacc;
  }
}

// ------------------------------- launch ---------------------------------------
extern "C" void kernel_launch(void* const* d_in, const int* in_sizes, int n_in,
                              void* d_out, int out_size, void* d_ws, size_t ws_size,
                              hipStream_t stream) {
  (void)in_sizes; (void)n_in; (void)out_size; (void)ws_size;
  const float* inputs = (const float*)d_in[0];
  const float* pos    = (const float*)d_in[1];
  const float* invd   = (const float*)d_in[2];
  const float* wn_w   = (const float*)d_in[3];
  const float* wn_g   = (const float*)d_in[5];
  const float* wn_be  = (const float*)d_in[6];
  const float* dn_w1  = (const float*)d_in[7];
  const float* dn_g1  = (const float*)d_in[9];
  const float* dn_be1 = (const float*)d_in[10];
  const float* dn_w2  = (const float*)d_in[11];
  const float* dn_b2  = (const float*)d_in[12];
  const float* lin_w  = (const float*)d_in[13];
  const float* lin_b  = (const float*)d_in[14];
  float* outp = (float*)d_out;

  char* ws = (char*)d_ws;
  float*    prm      = (float*)(ws + 1024);                   // 640 B
  float4*   pos4     = (float4*)(ws + 4096);                  // 256 KB
  int*      nnidx    = (int*)(ws + (size_t)(1u << 19));       // 1 MB   [0.5, 1.5)
  float*    dsbuf    = (float*)(ws + (size_t)(3u << 19));     // 1 MB   [1.5, 2.5)
  ushort*   inT      = (ushort*)(ws + (size_t)(5u << 19));    // 2 MB   [2.5, 4.5)
  ushort*   LTf      = (ushort*)(ws + (size_t)(9u << 19));    // 256 KB [4.5, 4.75)
  unsigned* T0g      = (unsigned*)(ws + (size_t)(19u << 18)); // 64 KB  [4.75, 4.8125)
  double*   stp      = (double*)(ws + (size_t)(5u << 20));    // 512 KB [5, 5.5)
  uint4*    partials = (uint4*)(ws + (size_t)(11u << 19));    // 8 MB   [5.5, 13.5)
  uint4*    surv     = (uint4*)(ws + (size_t)(11u << 19));    // 16 MB  [5.5, 21.5) aliases dead partials

  prep_all<<<384, 256, 0, stream>>>(pos, pos4, inputs, inT, lin_w, LTf);
  knn_sub<<<dim3(64, 8), 256, 0, stream>>>(pos4, partials);
  knn_thresh<<<256, 64, 0, stream>>>(partials, T0g);
  knn_filter<<<dim3(64, 16), 256, 0, stream>>>(pos4, T0g, surv);
  knn_final<<<1024, 256, 0, stream>>>(pos4, invd, surv, nnidx, dsbuf, stp);
  finalize_params<<<1, 256, 0, stream>>>(stp, wn_w, wn_g, wn_be, dn_w1, dn_g1, dn_be1, prm);
  fused<<<1024, 256, 0, stream>>>(inT, pos4, nnidx, dsbuf, prm, dn_w2, dn_b2, LTf, lin_b, outp);
}

// Round 26
// 135.746 us; speedup vs baseline: 1.1401x; 1.0049x over previous
//
#include <hip/hip_runtime.h>
#include <math.h>

// Problem constants
#define NB 4
#define NC 64
#define NPTS 4096
#define NROWS (NB*NPTS)      // 16384

typedef __attribute__((ext_vector_type(4))) float f32x4;
typedef __bf16 bf16x8 __attribute__((ext_vector_type(8)));

__device__ __forceinline__ ushort f2bf(float f) {
  unsigned u = __float_as_uint(f);
  u = (u + 0x7FFFu + ((u >> 16) & 1u)) >> 16;   // RNE
  return (ushort)u;
}
__device__ __forceinline__ unsigned pk2(float lo, float hi) {
  return (unsigned)f2bf(lo) | ((unsigned)f2bf(hi) << 16);
}

// ---------------- top-16 insertion (sorted ascending, dd[15]=max) -------------
__device__ __forceinline__ void insert16(double dist, int j, double (&dd)[16], int (&ii)[16]) {
  double cd = dist; int ci = j;
#pragma unroll
  for (int s = 0; s < 16; ++s) {
    double od = dd[s]; int oi = ii[s];
    bool c = cd < od;
    dd[s] = c ? cd : od;
    ii[s] = c ? ci : oi;
    cd = c ? od : cd;
    ci = c ? oi : ci;
  }
}

__device__ __forceinline__ void bub16u(unsigned key, unsigned (&t)[16]) {
#pragma unroll
  for (int q2 = 0; q2 < 16; ++q2) {
    unsigned lo = min(key, t[q2]);
    key = max(key, t[q2]);
    t[q2] = lo;
  }
}

// DPP row_ror double helper (rotates both 32-bit halves by the same lanes)
#define DPPD(RES, V, CTRL) { \
  long long bits_ = __double_as_longlong(V); \
  int lo_ = (int)bits_, hi_ = (int)(bits_ >> 32); \
  int lo2_ = __builtin_amdgcn_update_dpp(0, lo_, CTRL, 0xF, 0xF, true); \
  int hi2_ = __builtin_amdgcn_update_dpp(0, hi_, CTRL, 0xF, 0xF, true); \
  RES = __longlong_as_double(((long long)(unsigned)lo2_) | ((long long)hi2_ << 32)); }

// full-wave f64 sum: DPP rotate-reduce within 16-lane rows, then 2 cross-row shfls
__device__ __forceinline__ double wave_reduce(double v) {
  double t2;
  DPPD(t2, v, 0x121) v += t2;
  DPPD(t2, v, 0x122) v += t2;
  DPPD(t2, v, 0x124) v += t2;
  DPPD(t2, v, 0x128) v += t2;
  v += __shfl_xor(v, 16, 64);
  v += __shfl_xor(v, 32, 64);
  return v;
}

// ---------------- Kernel P: fused prep (pack pos4 | transpose inT | pack LTf) --
__global__ __launch_bounds__(256) void prep_all(const float* __restrict__ pos,
                                                float4* __restrict__ pos4,
                                                const float* __restrict__ in,
                                                ushort* __restrict__ inT,
                                                const float* __restrict__ lin_w,
                                                ushort* __restrict__ LTf) {
  __shared__ float tile[64][68];
  int t = threadIdx.x;
  int bid = blockIdx.x;
  if (bid < 64) {
    int g = bid * 256 + t;
    int b = g >> 12, n = g & (NPTS - 1);
    const float* pb = pos + b * 3 * NPTS;
    pos4[g] = make_float4(pb[n], pb[NPTS + n], pb[2 * NPTS + n], 0.f);
  } else if (bid < 320) {
    int blk = bid - 64;
    int b = blk >> 6;
    int n0 = (blk & 63) << 6;
    {
      int c = t >> 2, q = t & 3;
      const float* src = in + ((size_t)(b * 64 + c)) * NPTS + n0 + q * 16;
      float4 v0 = ((const float4*)src)[0];
      float4 v1 = ((const float4*)src)[1];
      float4 v2 = ((const float4*)src)[2];
      float4 v3 = ((const float4*)src)[3];
      *(float4*)&tile[c][q * 16 + 0] = v0;
      *(float4*)&tile[c][q * 16 + 4] = v1;
      *(float4*)&tile[c][q * 16 + 8] = v2;
      *(float4*)&tile[c][q * 16 + 12] = v3;
    }
    __syncthreads();
    {
      int nl = t >> 2, cq = t & 3;
      unsigned pk[8];
#pragma unroll
      for (int i = 0; i < 8; ++i) {
        float lo = tile[cq * 16 + 2 * i][nl];
        float hi = tile[cq * 16 + 2 * i + 1][nl];
        pk[i] = pk2(lo, hi);
      }
      uint4* dst = (uint4*)(inT + ((size_t)(b * NPTS + n0 + nl)) * 64 + cq * 16);
      dst[0] = make_uint4(pk[0], pk[1], pk[2], pk[3]);
      dst[1] = make_uint4(pk[4], pk[5], pk[6], pk[7]);
    }
  } else {
    int g = (bid - 320) * 256 + t;      // 16384
    int l = g & 63, ot = (g >> 6) & 3, s = g >> 8;
    int o = ot * 16 + (l & 15);
    const float* src = lin_w + (size_t)o * 2048 + s * 32 + (l >> 4) * 8;
    float4 u0 = ((const float4*)src)[0];
    float4 u1 = ((const float4*)src)[1];
    ((uint4*)LTf)[g] = make_uint4(pk2(u0.x, u0.y), pk2(u0.z, u0.w),
                                  pk2(u1.x, u1.y), pk2(u1.z, u1.w));
  }
}

// ---------------- Kernel S: subset partial KNN --------------------------------
__global__ __launch_bounds__(256) void knn_sub(const float4* __restrict__ pos4,
                                               uint4* __restrict__ partials) {
  __shared__ float4 cand[128];
  int t = threadIdx.x;
  int row0 = blockIdx.x * 256;
  int b = row0 >> 12;
  int y = blockIdx.y;
  int j0 = (y >> 1) * 1024 + (y & 1) * 128;
  const float4* pb = pos4 + b * NPTS;
  if (t < 128) cand[t] = pb[j0 + t];
  __syncthreads();
  float4 q = pb[(row0 + t) & (NPTS - 1)];
  unsigned dd[16];
#pragma unroll
  for (int s = 0; s < 16; ++s) dd[s] = 0xFFFFFFFFu;
#pragma unroll 4
  for (int jj = 0; jj < 128; ++jj) {
    float4 c = cand[jj];
    float dx = q.x - c.x, dy = q.y - c.y, dz = q.z - c.z;
    float d = fmaf(dx, dx, fmaf(dy, dy, dz * dz));
    unsigned key = (__float_as_uint(d) & 0xFFFFF000u) | (unsigned)(j0 + jj);
#pragma unroll
    for (int s = 0; s < 16; ++s) {
      unsigned lo = min(key, dd[s]);
      key = max(key, dd[s]);
      dd[s] = lo;
    }
  }
  uint4* po = partials + ((size_t)y * NROWS + row0 + t) * 4;
  po[0] = make_uint4(dd[0], dd[1], dd[2], dd[3]);
  po[1] = make_uint4(dd[4], dd[5], dd[6], dd[7]);
  po[2] = make_uint4(dd[8], dd[9], dd[10], dd[11]);
  po[3] = make_uint4(dd[12], dd[13], dd[14], dd[15]);
}

// ---------------- Kernel T: per-row filter threshold (batched LDS staging) ----
__global__ __launch_bounds__(64) void knn_thresh(const uint4* __restrict__ partials,
                                                 unsigned* __restrict__ T0g) {
  __shared__ unsigned sl[64 * 132];      // 33792 B
  int tid = threadIdx.x;
  int row0 = blockIdx.x * 64;
  uint4* sl4 = (uint4*)sl;
  size_t base = (size_t)row0 * 4 + tid;
#define TW(IT, V) { int g2 = ((IT) & 3) * 64 + tid; \
                    sl4[(g2 >> 2) * 33 + ((IT) >> 2) * 4 + (g2 & 3)] = (V); }
#define TB(B) { int IT0 = (B) * 8; \
  uint4 w0 = partials[(size_t)((IT0+0)>>2)*(NROWS*4) + ((IT0+0)&3)*64 + base]; \
  uint4 w1 = partials[(size_t)((IT0+1)>>2)*(NROWS*4) + ((IT0+1)&3)*64 + base]; \
  uint4 w2 = partials[(size_t)((IT0+2)>>2)*(NROWS*4) + ((IT0+2)&3)*64 + base]; \
  uint4 w3 = partials[(size_t)((IT0+3)>>2)*(NROWS*4) + ((IT0+3)&3)*64 + base]; \
  uint4 w4 = partials[(size_t)((IT0+4)>>2)*(NROWS*4) + ((IT0+4)&3)*64 + base]; \
  uint4 w5 = partials[(size_t)((IT0+5)>>2)*(NROWS*4) + ((IT0+5)&3)*64 + base]; \
  uint4 w6 = partials[(size_t)((IT0+6)>>2)*(NROWS*4) + ((IT0+6)&3)*64 + base]; \
  uint4 w7 = partials[(size_t)((IT0+7)>>2)*(NROWS*4) + ((IT0+7)&3)*64 + base]; \
  TW(IT0+0,w0) TW(IT0+1,w1) TW(IT0+2,w2) TW(IT0+3,w3) \
  TW(IT0+4,w4) TW(IT0+5,w5) TW(IT0+6,w6) TW(IT0+7,w7) }
  TB(0) TB(1) TB(2) TB(3)
#undef TB
#undef TW
  __syncthreads();
  unsigned top[16];
#pragma unroll
  for (int s = 0; s < 16; ++s) top[s] = 0xFFFFFFFFu;
  const unsigned* my = sl + tid * 132;
  for (int y = 0; y < 8; ++y) {
#pragma unroll 4
    for (int s = 0; s < 16; ++s) {
      unsigned key = my[y * 16 + s];
      if (key >= top[15]) break;         // chunk list sorted ascending
#pragma unroll
      for (int q2 = 0; q2 < 16; ++q2) {
        unsigned lo = min(key, top[q2]);
        key = max(key, top[q2]);
        top[q2] = lo;
      }
    }
  }
  T0g[row0 + tid] = top[15] & 0xFFFFF000u;
}

// ---------------- Kernel F: scan 256-cand chunk + exec-gated sorted top-16 ----
__global__ __launch_bounds__(256) void knn_filter(const float4* __restrict__ pos4,
                                                  const unsigned* __restrict__ T0g,
                                                  uint4* __restrict__ surv) {
  __shared__ float4 cand[256];           // 4 KB
  __shared__ unsigned lq[256 * 28];      // 28 KB
  int t = threadIdx.x;
  int row0 = blockIdx.x * 256;
  int b = row0 >> 12;
  int y = blockIdx.y;
  int j0 = y * 256;
  const float4* pb = pos4 + b * NPTS;
  cand[t] = pb[j0 + t];
  __syncthreads();
  int r = row0 + t;
  float4 q = pb[r & (NPTS - 1)];
  unsigned T = T0g[r];
  unsigned cnt = 0;
  unsigned* myq = lq + t * 28;
#pragma unroll 4
  for (int jj = 0; jj < 256; ++jj) {
    float4 c = cand[jj];
    float dx = q.x - c.x, dy = q.y - c.y, dz = q.z - c.z;
    float d = fmaf(dx, dx, fmaf(dy, dy, dz * dz));
    unsigned m = __float_as_uint(d) & 0xFFFFF000u;
    if (m <= T) {
      if (cnt < 28u) myq[cnt] = m | (unsigned)(j0 + jj);
      ++cnt;
    }
  }
  cnt = cnt < 28u ? cnt : 28u;
  unsigned t16[16];
#pragma unroll
  for (int s = 0; s < 16; ++s) t16[s] = 0xFFFFFFFFu;
  const uint4* qsrc = (const uint4*)myq;
  uint4 q0 = qsrc[0], q1 = qsrc[1], q2 = qsrc[2], q3 = qsrc[3],
        q4 = qsrc[4], q5 = qsrc[5], q6 = qsrc[6];
#define SIN(K, I) { if ((I) < cnt) bub16u((K), t16); }
  SIN(q0.x,0u) SIN(q0.y,1u) SIN(q0.z,2u) SIN(q0.w,3u)
  SIN(q1.x,4u) SIN(q1.y,5u) SIN(q1.z,6u) SIN(q1.w,7u)
  SIN(q2.x,8u) SIN(q2.y,9u) SIN(q2.z,10u) SIN(q2.w,11u)
  SIN(q3.x,12u) SIN(q3.y,13u) SIN(q3.z,14u) SIN(q3.w,15u)
  SIN(q4.x,16u) SIN(q4.y,17u) SIN(q4.z,18u) SIN(q4.w,19u)
  SIN(q5.x,20u) SIN(q5.y,21u) SIN(q5.z,22u) SIN(q5.w,23u)
  SIN(q6.x,24u) SIN(q6.y,25u) SIN(q6.z,26u) SIN(q6.w,27u)
#undef SIN
  uint4* dst = surv + ((size_t)r * 16 + y) * 4;
  dst[0] = make_uint4(t16[0], t16[1], t16[2], t16[3]);
  dst[1] = make_uint4(t16[4], t16[5], t16[6], t16[7]);
  dst[2] = make_uint4(t16[8], t16[9], t16[10], t16[11]);
  dst[3] = make_uint4(t16[12], t16[13], t16[14], t16[15]);
}

// ---------------- Kernel M: DPP tournament merge + tie-gated exact re-rank ----
__global__ __launch_bounds__(256) void knn_final(const float4* __restrict__ pos4,
                                                 const float* __restrict__ invd,
                                                 const uint4* __restrict__ surv,
                                                 int* __restrict__ nn_idx,
                                                 float* __restrict__ dsbuf,
                                                 double* __restrict__ stp) {
  int t = threadIdx.x;
  int ln = t & 15;                       // lane within row-group = chunk id
  int r = blockIdx.x * 16 + (t >> 4);
  int b = r >> 12, n = r & (NPTS - 1);

  const uint4* sp = surv + ((size_t)r * 16 + ln) * 4;
  uint4 u0 = sp[0], u1 = sp[1], u2 = sp[2], u3 = sp[3];
  unsigned h0=u0.x,h1=u0.y,h2=u0.z,h3=u0.w,h4=u1.x,h5=u1.y,h6=u1.z,h7=u1.w,
           h8=u2.x,h9=u2.y,h10=u2.z,h11=u2.w,h12=u3.x,h13=u3.y,h14=u3.z,h15=u3.w;
  unsigned t0,t1,t2,t3,t4,t5,t6,t7,t8,t9,t10,t11,t12,t13,t14,t15,t16;
#define UMIN_DPP(M, CTRL) \
  M = min(M, (unsigned)__builtin_amdgcn_update_dpp(0, (int)(M), CTRL, 0xF, 0xF, true));
#define RND(TT) { unsigned m = h0; \
  UMIN_DPP(m, 0x121) UMIN_DPP(m, 0x122) UMIN_DPP(m, 0x124) UMIN_DPP(m, 0x128) \
  TT = m; bool pop = (h0 == m); \
  h0 = pop ? h1 : h0;  h1 = pop ? h2 : h1;  h2 = pop ? h3 : h2; \
  h3 = pop ? h4 : h3;  h4 = pop ? h5 : h4;  h5 = pop ? h6 : h5; \
  h6 = pop ? h7 : h6;  h7 = pop ? h8 : h7;  h8 = pop ? h9 : h8; \
  h9 = pop ? h10 : h9; h10 = pop ? h11 : h10; h11 = pop ? h12 : h11; \
  h12 = pop ? h13 : h12; h13 = pop ? h14 : h13; h14 = pop ? h15 : h14; \
  h15 = pop ? 0xFFFFFFFFu : h15; }
  RND(t0) RND(t1) RND(t2) RND(t3) RND(t4) RND(t5) RND(t6) RND(t7)
  RND(t8) RND(t9) RND(t10) RND(t11) RND(t12) RND(t13) RND(t14) RND(t15)
  RND(t16)

  const float4* pb = pos4 + b * NPTS;
  float4 qp = pb[n];
  double xi = qp.x, yi = qp.y, zi = qp.z;

  int jm;
  bool tie = ((t15 & 0xFFFFF000u) == (t16 & 0xFFFFF000u));
  if (!tie) {
    unsigned tm = t0;
    tm = (ln == 1) ? t1 : tm;   tm = (ln == 2) ? t2 : tm;
    tm = (ln == 3) ? t3 : tm;   tm = (ln == 4) ? t4 : tm;
    tm = (ln == 5) ? t5 : tm;   tm = (ln == 6) ? t6 : tm;
    tm = (ln == 7) ? t7 : tm;   tm = (ln == 8) ? t8 : tm;
    tm = (ln == 9) ? t9 : tm;   tm = (ln == 10) ? t10 : tm;
    tm = (ln == 11) ? t11 : tm; tm = (ln == 12) ? t12 : tm;
    tm = (ln == 13) ? t13 : tm; tm = (ln == 14) ? t14 : tm;
    tm = (ln == 15) ? t15 : tm;
    jm = (int)(tm & 0xFFFu);
  } else {
    unsigned t17, t18, t19, t20, t21, t22, t23;
    RND(t17) RND(t18) RND(t19) RND(t20) RND(t21) RND(t22) RND(t23)
    double dd[16]; int ii[16];
#pragma unroll
    for (int s = 0; s < 16; ++s) { dd[s] = 1e300; ii[s] = 0; }
#define RRK(TT) if (TT != 0xFFFFFFFFu) { int j = (int)(TT & 0xFFFu); \
  float4 cj = pb[j]; \
  double dx = xi - (double)cj.x, dy = yi - (double)cj.y, dz = zi - (double)cj.z; \
  double dist = dx * dx + dy * dy + dz * dz; \
  if (dist < dd[15]) insert16(dist, j, dd, ii); }
    RRK(t0) RRK(t1) RRK(t2) RRK(t3) RRK(t4) RRK(t5) RRK(t6) RRK(t7)
    RRK(t8) RRK(t9) RRK(t10) RRK(t11) RRK(t12) RRK(t13) RRK(t14) RRK(t15)
    RRK(t16) RRK(t17) RRK(t18) RRK(t19) RRK(t20) RRK(t21) RRK(t22) RRK(t23)
#undef RRK
    int jj2 = ii[0];
#pragma unroll
    for (int s = 1; s < 16; ++s) jj2 = (ln == s) ? ii[s] : jj2;
    jm = jj2;
  }
#undef RND
#undef UMIN_DPP

  nn_idx[(size_t)r * 16 + ln] = jm;
  const float* ivb = invd + b * NPTS;
  float v = ivb[jm];
  float vmax = v;
#define FMAX_DPP(X, CTRL) { \
    float y_ = __int_as_float(__builtin_amdgcn_update_dpp(0, __float_as_int(X), CTRL, 0xF, 0xF, true)); \
    X = fmaxf(X, y_); }
  FMAX_DPP(vmax, 0x121) FMAX_DPP(vmax, 0x122)
  FMAX_DPP(vmax, 0x124) FMAX_DPP(vmax, 0x128)
#undef FMAX_DPP
  float x = v / vmax;
  dsbuf[(size_t)r * 16 + ln] = x;

  double sx = x, sxx = (double)x * (double)x;
  float4 pj = pb[jm];
  double lx = (double)pj.x - xi, lyv = (double)pj.y - yi, lzv = (double)pj.z - zi;
  double l1x = lx, l1y = lyv, l1z = lzv;
  double lxx = lx * lx, lyy = lyv * lyv, lzz = lzv * lzv;
  double lxy = lx * lyv, lxz = lx * lzv, lyz = lyv * lzv;
  sx  = wave_reduce(sx);  sxx = wave_reduce(sxx);
  l1x = wave_reduce(l1x); l1y = wave_reduce(l1y); l1z = wave_reduce(l1z);
  lxx = wave_reduce(lxx); lyy = wave_reduce(lyy); lzz = wave_reduce(lzz);
  lxy = wave_reduce(lxy); lxz = wave_reduce(lxz); lyz = wave_reduce(lyz);
  if ((t & 63) == 0) {
    double* o = stp + ((size_t)blockIdx.x * 4 + (t >> 6)) * 16;
    o[0] = sx;  o[1] = sxx;
    o[2] = l1x; o[3] = l1y; o[4] = l1z;
    o[5] = lxx; o[6] = lyy; o[7] = lzz;
    o[8] = lxy; o[9] = lxz; o[10] = lyz;
  }
}

// ---------------- Kernel 3: reduce 4096 partials + fold BN --------------------
__global__ __launch_bounds__(256) void finalize_params(const double* __restrict__ stp,
                                const float* __restrict__ wn_w,
                                const float* __restrict__ wn_g,
                                const float* __restrict__ wn_be,
                                const float* __restrict__ dn_w1,
                                const float* __restrict__ dn_g1,
                                const float* __restrict__ dn_be1,
                                float* __restrict__ prm) {
  __shared__ double part[16][16];
  __shared__ double red[11];
  const double M = (double)NROWS * 16.0;  // 262144
  int t = threadIdx.x;
  {
    int c = t & 15, ch = t >> 4;         // 16 chunks of 256 wave-partials
    double s = 0.0;
#pragma unroll 8
    for (int w = 0; w < 256; ++w) s += stp[(size_t)(ch * 256 + w) * 16 + c];
    part[ch][c] = s;
  }
  __syncthreads();
  if (t < 11) {
    double s = 0.0;
#pragma unroll
    for (int ch = 0; ch < 16; ++ch) s += part[ch][t];
    red[t] = s;
  }
  __syncthreads();
  if (t < 32) {
    double m0 = red[2] / M, m1 = red[3] / M, m2 = red[4] / M;
    double cxx = red[5] / M - m0 * m0, cyy = red[6] / M - m1 * m1, czz = red[7] / M - m2 * m2;
    double cxy = red[8] / M - m0 * m1, cxz = red[9] / M - m0 * m2, cyz = red[10] / M - m1 * m2;
    double w0 = wn_w[t * 3], w1 = wn_w[t * 3 + 1], w2 = wn_w[t * 3 + 2];
    double var = w0 * w0 * cxx + w1 * w1 * cyy + w2 * w2 * czz
               + 2.0 * (w0 * w1 * cxy + w0 * w2 * cxz + w1 * w2 * cyz);
    double alpha = (double)wn_g[t] / sqrt(var + 1e-5);
    double a0 = alpha * w0, a1 = alpha * w1, a2 = alpha * w2;
    prm[t * 3] = (float)a0; prm[t * 3 + 1] = (float)a1; prm[t * 3 + 2] = (float)a2;
    prm[96 + t] = (float)((double)wn_be[t] - (a0 * m0 + a1 * m1 + a2 * m2));
  } else if (t < 48) {
    int ch = t - 32;
    double mx = red[0] / M;
    double vx = red[1] / M - mx * mx;
    double w = dn_w1[ch];
    double alpha = (double)dn_g1[ch] * w / sqrt(w * w * vx + 1e-5);
    prm[128 + ch] = (float)alpha;
    prm[144 + ch] = (float)((double)dn_be1[ch] - alpha * mx);
  }
}

// ------- Fused kernel: gather + DensityNet + WeightNet + MFMA matmul + GEMM ---
#define XSTR 2320   // bytes per point: 16 k-rows * 144 B + 16 pad
#define WTOFF 37120 // = 16*XSTR
#define WTSTR 1040  // bytes per point: 32 w-rows * 32 B + 16 pad

__global__ __launch_bounds__(256, 3) void fused(const ushort* __restrict__ inT,
                                                const float4* __restrict__ pos4,
                                                const int* __restrict__ nn_idx,
                                                const float* __restrict__ dsbuf,
                                                const float* __restrict__ prm_g,
                                                const float* __restrict__ dn_w2,
                                                const float* __restrict__ dn_b2,
                                                const ushort* __restrict__ LTf,
                                                const float* __restrict__ lin_b,
                                                float* __restrict__ out) {
  __shared__ __align__(16) char smem[53760];
  char* xraw = smem;
  char* wT = smem + WTOFF;
  int t = threadIdx.x;
  int blk = blockIdx.x;          // 1024 tiles of 16 points
  int b = blk >> 8;
  int n0 = (blk & 255) << 4;
  // ---- phase 1: stage. thread (k = t>>4, p = t&15) ----
  {
    int k = t >> 4, p = t & 15;
    int r = blk * 16 + p;
    int n = n0 + p;
    int j = nn_idx[(size_t)r * 16 + k];
    float4 pj = pos4[b * NPTS + j];
    float4 pn = pos4[b * NPTS + n];
    float lx = pj.x - pn.x, ly = pj.y - pn.y, lz = pj.z - pn.z;
    float xr = dsbuf[(size_t)r * 16 + k];
    float sacc = dn_b2[0];
#pragma unroll
    for (int ch = 0; ch < 16; ++ch)
      sacc = fmaf(dn_w2[ch], fmaxf(fmaf(prm_g[128 + ch], xr, prm_g[144 + ch]), 0.f), sacc);
    float ds = 1.f / (1.f + expf(-sacc));
    const uint4* srcx = (const uint4*)(inT + ((size_t)(b * NPTS + j)) * 64);
    uint4* dstx = (uint4*)(xraw + p * XSTR + k * 144);
#pragma unroll
    for (int i = 0; i < 8; ++i) dstx[i] = srcx[i];
    char* wr = wT + p * WTSTR + k * 2;
#pragma unroll
    for (int w = 0; w < 32; ++w) {
      float v = fmaf(prm_g[w * 3], lx,
                fmaf(prm_g[w * 3 + 1], ly,
                fmaf(prm_g[w * 3 + 2], lz, prm_g[96 + w])));
      *(ushort*)(wr + w * 32) = f2bf(fmaxf(v, 0.f) * ds);
    }
  }
  __syncthreads();
  // ---- phase 2: MFMA per-point matmul. wave wv -> points wv*4..wv*4+3 ----
  int wv = t >> 6;
  int l = t & 63;
  int lr = l & 15;
  int q = l >> 4;
  int kq8 = (q & 1) * 1152;      // (q&1)*8 rows * 144 B
  int swz = (lr & 7) << 4;
  const f32x4 zf = (f32x4)0.f;
  uint4 zu = make_uint4(0u, 0u, 0u, 0u);

#define DECLD(IT) unsigned d##IT##_0,d##IT##_1,d##IT##_2,d##IT##_3,d##IT##_4, \
  d##IT##_5,d##IT##_6,d##IT##_7,d##IT##_8,d##IT##_9,d##IT##_10,d##IT##_11, \
  d##IT##_12,d##IT##_13,d##IT##_14,d##IT##_15;
  DECLD(0) DECLD(1) DECLD(2) DECLD(3)
#undef DECLD

#define LOADB(BU, NI, XP) { \
    const char* xb = (XP) + ((NI) * 16 + lr) * 2; \
    unsigned e0 = *(const ushort*)(xb); \
    unsigned e1 = *(const ushort*)(xb + 144); \
    unsigned e2 = *(const ushort*)(xb + 288); \
    unsigned e3 = *(const ushort*)(xb + 432); \
    unsigned e4 = *(const ushort*)(xb + 576); \
    unsigned e5 = *(const ushort*)(xb + 720); \
    unsigned e6 = *(const ushort*)(xb + 864); \
    unsigned e7 = *(const ushort*)(xb + 1008); \
    BU = make_uint4(e0 | (e1 << 16), e2 | (e3 << 16), \
                    e4 | (e5 << 16), e6 | (e7 << 16)); }

#define MM(AF, BF, RA, RB) { \
    f32x4 D = __builtin_amdgcn_mfma_f32_16x16x32_bf16(AF, BF, zf, 0, 0, 0); \
    RA = pk2(D.x, D.y); RB = pk2(D.z, D.w); }

#define DO_POINT(IT) { \
    int p = wv * 4 + (IT); \
    const char* wtp = wT + p * WTSTR; \
    const char* xp = xraw + p * XSTR + kq8; \
    uint4 a0u = zu, a1u = zu; \
    if (q < 2) { \
      a0u = *(const uint4*)(wtp + lr * 32 + q * 16); \
      a1u = *(const uint4*)(wtp + (16 + lr) * 32 + q * 16); \
    } \
    bf16x8 A0 = *reinterpret_cast<bf16x8*>(&a0u); \
    bf16x8 A1 = *reinterpret_cast<bf16x8*>(&a1u); \
    uint4 b0u, b1u, b2u, b3u; \
    LOADB(b0u, 0, xp) LOADB(b1u, 1, xp) LOADB(b2u, 2, xp) LOADB(b3u, 3, xp) \
    bf16x8 B0 = *reinterpret_cast<bf16x8*>(&b0u); \
    bf16x8 B1 = *reinterpret_cast<bf16x8*>(&b1u); \
    bf16x8 B2 = *reinterpret_cast<bf16x8*>(&b2u); \
    bf16x8 B3 = *reinterpret_cast<bf16x8*>(&b3u); \
    MM(A0, B0, d##IT##_0, d##IT##_1)   MM(A0, B1, d##IT##_2, d##IT##_3) \
    MM(A0, B2, d##IT##_4, d##IT##_5)   MM(A0, B3, d##IT##_6, d##IT##_7) \
    MM(A1, B0, d##IT##_8, d##IT##_9)   MM(A1, B1, d##IT##_10, d##IT##_11) \
    MM(A1, B2, d##IT##_12, d##IT##_13) MM(A1, B3, d##IT##_14, d##IT##_15) }

  DO_POINT(0) DO_POINT(1) DO_POINT(2) DO_POINT(3)
#undef DO_POINT
#undef MM
#undef LOADB
  __syncthreads();   // all MFMA reads of xraw/wT complete
  // ---- phases 3/4 in two K-halves over 32 KB aq aliased on xraw ----
  int hq = q >> 1;
  int m0 = (q & 1) * 2;
  const uint4* Lq = (const uint4*)LTf;
  f32x4 cacc0 = (f32x4)0.f, cacc1 = (f32x4)0.f;   // dual accumulators (chain/2)
#define STT(IT, MI, NIL, RA, RB) { \
    int p = wv * 4 + (IT); \
    int h = (MI) * 2 + hq; \
    int base = (((NIL) * 16 + lr)) * 1024 + (p + 16 * h) * 16 + m0 * 4; \
    *(unsigned*)(smem + (base ^ swz)) = RA; \
    *(unsigned*)(smem + ((base + 4) ^ swz)) = RB; }
  // half A: NI 0,1  -> local rows 0..31
#define STPA(IT) \
    STT(IT,0,0,d##IT##_0,d##IT##_1)   STT(IT,0,1,d##IT##_2,d##IT##_3) \
    STT(IT,1,0,d##IT##_8,d##IT##_9)   STT(IT,1,1,d##IT##_10,d##IT##_11)
  STPA(0) STPA(1) STPA(2) STPA(3)
#undef STPA
  __syncthreads();
#pragma unroll 4
  for (int s = 0; s < 32; ++s) {
    uint4 ua = *(const uint4*)(smem + (((s * 64 + l) * 16) ^ ((s & 7) << 4)));
    uint4 ub = Lq[(s * 4 + wv) * 64 + l];
    bf16x8 A = *reinterpret_cast<bf16x8*>(&ua);
    bf16x8 B = *reinterpret_cast<bf16x8*>(&ub);
    if (s & 1) cacc1 = __builtin_amdgcn_mfma_f32_16x16x32_bf16(A, B, cacc1, 0, 0, 0);
    else       cacc0 = __builtin_amdgcn_mfma_f32_16x16x32_bf16(A, B, cacc0, 0, 0, 0);
  }
  __syncthreads();   // phase-4a reads done before overwrite
  // half B: NI 2,3 -> local rows 0..31
#define STPB(IT) \
    STT(IT,0,0,d##IT##_4,d##IT##_5)   STT(IT,0,1,d##IT##_6,d##IT##_7) \
    STT(IT,1,0,d##IT##_12,d##IT##_13) STT(IT,1,1,d##IT##_14,d##IT##_15)
  STPB(0) STPB(1) STPB(2) STPB(3)
#undef STPB
#undef STT
  __syncthreads();
#pragma unroll 4
  for (int sl2 = 0; sl2 < 32; ++sl2) {
    int s = sl2 + 32;
    uint4 ua = *(const uint4*)(smem + (((sl2 * 64 + l) * 16) ^ ((sl2 & 7) << 4)));
    uint4 ub = Lq[(s * 4 + wv) * 64 + l];
    bf16x8 A = *reinterpret_cast<bf16x8*>(&ua);
    bf16x8 B = *reinterpret_cast<bf16x8*>(&ub);
    if (sl2 & 1) cacc1 = __builtin_amdgcn_mfma_f32_16x16x32_bf16(A, B, cacc1, 0, 0, 0);
    else         cacc0 = __builtin_amdgcn_mfma_f32_16x16x32_bf16(A, B, cacc0, 0, 0, 0);
  }
  // ---- epilogue ----
  {
    f32x4 cacc = cacc0 + cacc1;
    int o = wv * 16 + lr;
    float bias = lin_b[o];
    cacc.x += bias; cacc.y += bias; cacc.z += bias; cacc.w += bias;
    *(f32x4*)(out + ((size_t)(b * 64 + o)) * NPTS + n0 + q * 4) = cacc;
  }
}

// ------------------------------- launch ---------------------------------------
extern "C" void kernel_launch(void* const* d_in, const int* in_sizes, int n_in,
                              void* d_out, int out_size, void* d_ws, size_t ws_size,
                              hipStream_t stream) {
  (void)in_sizes; (void)n_in; (void)out_size; (void)ws_size;
  const float* inputs = (const float*)d_in[0];
  const float* pos    = (const float*)d_in[1];
  const float* invd   = (const float*)d_in[2];
  const float* wn_w   = (const float*)d_in[3];
  const float* wn_g   = (const float*)d_in[5];
  const float* wn_be  = (const float*)d_in[6];
  const float* dn_w1  = (const float*)d_in[7];
  const float* dn_g1  = (const float*)d_in[9];
  const float* dn_be1 = (const float*)d_in[10];
  const float* dn_w2  = (const float*)d_in[11];
  const float* dn_b2  = (const float*)d_in[12];
  const float* lin_w  = (const float*)d_in[13];
  const float* lin_b  = (const float*)d_in[14];
  float* outp = (float*)d_out;

  char* ws = (char*)d_ws;
  float*    prm      = (float*)(ws + 1024);                   // 640 B
  float4*   pos4     = (float4*)(ws + 4096);                  // 256 KB
  int*      nnidx    = (int*)(ws + (size_t)(1u << 19));       // 1 MB   [0.5, 1.5)
  float*    dsbuf    = (float*)(ws + (size_t)(3u << 19));     // 1 MB   [1.5, 2.5)
  ushort*   inT      = (ushort*)(ws + (size_t)(5u << 19));    // 2 MB   [2.5, 4.5)
  ushort*   LTf      = (ushort*)(ws + (size_t)(9u << 19));    // 256 KB [4.5, 4.75)
  unsigned* T0g      = (unsigned*)(ws + (size_t)(19u << 18)); // 64 KB  [4.75, 4.8125)
  double*   stp      = (double*)(ws + (size_t)(5u << 20));    // 512 KB [5, 5.5)
  uint4*    partials = (uint4*)(ws + (size_t)(11u << 19));    // 8 MB   [5.5, 13.5)
  uint4*    surv     = (uint4*)(ws + (size_t)(11u << 19));    // 16 MB  [5.5, 21.5) aliases dead partials

  prep_all<<<384, 256, 0, stream>>>(pos, pos4, inputs, inT, lin_w, LTf);
  knn_sub<<<dim3(64, 8), 256, 0, stream>>>(pos4, partials);
  knn_thresh<<<256, 64, 0, stream>>>(partials, T0g);
  knn_filter<<<dim3(64, 16), 256, 0, stream>>>(pos4, T0g, surv);
  knn_final<<<1024, 256, 0, stream>>>(pos4, invd, surv, nnidx, dsbuf, stp);
  finalize_params<<<1, 256, 0, stream>>>(stp, wn_w, wn_g, wn_be, dn_w1, dn_g1, dn_be1, prm);
  fused<<<1024, 256, 0, stream>>>(inT, pos4, nnidx, dsbuf, prm, dn_w2, dn_b2, LTf, lin_b, outp);
}